// Round 1
// baseline (4771.288 us; speedup 1.0000x reference)
//
#include <hip/hip_runtime.h>
#include <hip/hip_bf16.h>

// ---------------------------------------------------------------------------
// TransformerBlock forward, MI355X.
// Shapes: B=2, S=2048, D=2048, HQ=32, HKV=8, G=4, DH=64, DMLP=8192. T=B*S=4096.
// Key simplification: reference einsum 'bqkgd,bskd->bkqs' sums q over group
// dim -> fold Sum_g W_Q[kv*G+g] into one [2048][512] matrix; attention is then
// 8 ordinary heads/batch.
// Round-1 baseline: vector-FMA GEMMs (f32 acc, bf16 A, f32 B), flash attention.
// ---------------------------------------------------------------------------

using bf16 = __hip_bfloat16;

#define D_MODEL 2048
#define SEQ     2048
#define NB      2
#define NTOK    4096          // NB*SEQ
#define NKV     8
#define DHEAD   64
#define DMLP    8192
#define NQKV    1536          // 3*NKV*DHEAD

__device__ inline void storev(float* p, float v)  { *p = v; }
__device__ inline void storev(bf16* p, float v)   { *p = __float2bfloat16(v); }

// ---------------------------------------------------------------------------
// Build combined QKV weight [2048][1536] f32:
// cols 0..511   = sum_g W_Q[kv*4+g][d][e]   (kv-major, e inner)
// cols 512..1023  = W_K[kv][d][e]
// cols 1024..1535 = W_V[kv][d][e]
// ---------------------------------------------------------------------------
__global__ __launch_bounds__(256) void build_wqkv_kernel(
    const float* __restrict__ WQ, const float* __restrict__ WK,
    const float* __restrict__ WV, float* __restrict__ wqkv)
{
    int idx = blockIdx.x * 256 + threadIdx.x;
    if (idx >= D_MODEL * NQKV) return;
    int d = idx / NQKV, col = idx % NQKV;
    float val;
    if (col < 512) {
        int kv = col >> 6, e = col & 63;
        const float* base = WQ + ((size_t)(kv * 4) * D_MODEL + d) * DHEAD + e;
        const size_t hs = (size_t)D_MODEL * DHEAD;
        val = base[0] + base[hs] + base[2 * hs] + base[3 * hs];
    } else if (col < 1024) {
        int c = col - 512; int kv = c >> 6, e = c & 63;
        val = WK[((size_t)kv * D_MODEL + d) * DHEAD + e];
    } else {
        int c = col - 1024; int kv = c >> 6, e = c & 63;
        val = WV[((size_t)kv * D_MODEL + d) * DHEAD + e];
    }
    wqkv[idx] = val;
}

// ---------------------------------------------------------------------------
// RMSNorm (faithful: mu = mean(x), var = mean((x-mu)^2), out = x/sqrt(var+eps)*g+b
//          -- x divided, NOT centered). One block per row, bf16 output.
// ---------------------------------------------------------------------------
__global__ __launch_bounds__(256) void rmsnorm_kernel(
    const float* __restrict__ x, const float* __restrict__ g,
    const float* __restrict__ b, bf16* __restrict__ out)
{
    const int row = blockIdx.x;
    const int t = threadIdx.x;
    const float* xr = x + (size_t)row * D_MODEL;
    float4 a0 = *reinterpret_cast<const float4*>(xr + t * 8);
    float4 a1 = *reinterpret_cast<const float4*>(xr + t * 8 + 4);
    float v[8] = {a0.x, a0.y, a0.z, a0.w, a1.x, a1.y, a1.z, a1.w};
    float sum = 0.f, sumsq = 0.f;
    #pragma unroll
    for (int j = 0; j < 8; ++j) { sum += v[j]; sumsq += v[j] * v[j]; }
    #pragma unroll
    for (int o = 1; o < 64; o <<= 1) {
        sum   += __shfl_xor(sum, o);
        sumsq += __shfl_xor(sumsq, o);
    }
    __shared__ float rs[4], rq[4];
    if ((t & 63) == 0) { rs[t >> 6] = sum; rq[t >> 6] = sumsq; }
    __syncthreads();
    sum   = rs[0] + rs[1] + rs[2] + rs[3];
    sumsq = rq[0] + rq[1] + rq[2] + rq[3];
    const float mu  = sum * (1.f / D_MODEL);
    const float var = sumsq * (1.f / D_MODEL) - mu * mu;
    const float rstd = 1.f / sqrtf(var + 1e-5f);
    const int c = t * 8;
    float4 g0 = *reinterpret_cast<const float4*>(g + c);
    float4 g1 = *reinterpret_cast<const float4*>(g + c + 4);
    float4 b0 = *reinterpret_cast<const float4*>(b + c);
    float4 b1 = *reinterpret_cast<const float4*>(b + c + 4);
    float gg[8] = {g0.x, g0.y, g0.z, g0.w, g1.x, g1.y, g1.z, g1.w};
    float bb[8] = {b0.x, b0.y, b0.z, b0.w, b1.x, b1.y, b1.z, b1.w};
    bf16* op = out + (size_t)row * D_MODEL + c;
    #pragma unroll
    for (int j = 0; j < 8; ++j) op[j] = __float2bfloat16(v[j] * rstd * gg[j] + bb[j]);
}

// ---------------------------------------------------------------------------
// Vector GEMM: C[M][N](f32 acc) = A_bf16[M][K] * B_f32[K][N] (+bias)(relu)(+resid)
// 128x128 tile, BK=16, 256 threads, 8x8 microtile.
// ---------------------------------------------------------------------------
template<typename TC, bool BIAS, bool RELU, bool RESID>
__global__ __launch_bounds__(256) void gemm_kernel(
    const bf16* __restrict__ A, const float* __restrict__ B,
    TC* __restrict__ C, const float* __restrict__ bias,
    const float* __restrict__ resid, int M, int N, int K)
{
    __shared__ float As[16][132];   // transposed: As[k][row]
    __shared__ float Bs[16][132];   // natural:    Bs[k][col]
    const int t  = threadIdx.x;
    const int tx = t & 15, ty = t >> 4;
    const int row0 = blockIdx.y * 128, col0 = blockIdx.x * 128;

    const int arow = t & 127;            // A staging row
    const int akh  = (t >> 7) << 3;      // A staging k-half: 0 or 8
    const int brow = t >> 4;             // B staging k-row 0..15
    const int bcol = (t & 15) << 3;      // B staging col *8

    float acc[8][8];
    #pragma unroll
    for (int i = 0; i < 8; ++i)
        #pragma unroll
        for (int j = 0; j < 8; ++j) acc[i][j] = 0.f;

    for (int kt = 0; kt < K; kt += 16) {
        // global loads (before barrier so they overlap previous compute drain)
        const bf16* ap = A + (size_t)(row0 + arow) * K + (kt + akh);
        uint4 raw = *reinterpret_cast<const uint4*>(ap);
        const bf16* hp = reinterpret_cast<const bf16*>(&raw);
        float av[8];
        #pragma unroll
        for (int j = 0; j < 8; ++j) av[j] = __bfloat162float(hp[j]);

        const float* bp = B + (size_t)(kt + brow) * N + (col0 + bcol);
        float4 b0 = *reinterpret_cast<const float4*>(bp);
        float4 b1 = *reinterpret_cast<const float4*>(bp + 4);

        __syncthreads();   // previous iteration's LDS reads done
        #pragma unroll
        for (int j = 0; j < 8; ++j) As[akh + j][arow] = av[j];
        *reinterpret_cast<float4*>(&Bs[brow][bcol])     = b0;
        *reinterpret_cast<float4*>(&Bs[brow][bcol + 4]) = b1;
        __syncthreads();

        #pragma unroll
        for (int k = 0; k < 16; ++k) {
            float4 a0 = *reinterpret_cast<const float4*>(&As[k][ty * 8]);
            float4 a1 = *reinterpret_cast<const float4*>(&As[k][ty * 8 + 4]);
            float4 c0 = *reinterpret_cast<const float4*>(&Bs[k][tx * 8]);
            float4 c1 = *reinterpret_cast<const float4*>(&Bs[k][tx * 8 + 4]);
            float ar[8] = {a0.x, a0.y, a0.z, a0.w, a1.x, a1.y, a1.z, a1.w};
            float br[8] = {c0.x, c0.y, c0.z, c0.w, c1.x, c1.y, c1.z, c1.w};
            #pragma unroll
            for (int i = 0; i < 8; ++i)
                #pragma unroll
                for (int j = 0; j < 8; ++j)
                    acc[i][j] = fmaf(ar[i], br[j], acc[i][j]);
        }
    }

    #pragma unroll
    for (int i = 0; i < 8; ++i) {
        const int r = row0 + ty * 8 + i;
        const size_t base = (size_t)r * N + col0 + tx * 8;
        #pragma unroll
        for (int j = 0; j < 8; ++j) {
            float v = acc[i][j];
            if constexpr (BIAS)  v += bias[col0 + tx * 8 + j];
            if constexpr (RELU)  v = fmaxf(v, 0.f);
            if constexpr (RESID) v += resid[base + j];
            storev(&C[base + j], v);
        }
    }
}

// ---------------------------------------------------------------------------
// Flash attention, one block per (qtile=64 rows, kv head, batch).
// qkv f32 [NTOK][1536]: q cols 0..511 (pre-group-summed), k 512+, v 1024+.
// scores scaled by 1/8 (folded into q load); causal mask; online softmax.
// z out bf16 [NTOK][512] (kv-major, d inner).
// ---------------------------------------------------------------------------
__global__ __launch_bounds__(256) void attn_kernel(
    const float* __restrict__ qkv, bf16* __restrict__ z)
{
    const int qt = blockIdx.x;      // 0..31
    const int kv = blockIdx.y;      // 0..7
    const int b  = blockIdx.z;      // 0..1
    const int t  = threadIdx.x;
    const int r  = t >> 2;          // 0..63 (query row in tile)
    const int cs = (t & 3) * 16;    // owned col segment

    __shared__ float Kx[64][68];
    __shared__ float Vx[64][68];
    __shared__ float P [64][68];

    const int q_glob = qt * 64 + r;

    // q row -> registers, pre-scaled by 1/sqrt(64)
    float qreg[64];
    {
        const float* qp = qkv + ((size_t)(b * SEQ + qt * 64 + r)) * NQKV + kv * 64;
        #pragma unroll
        for (int i = 0; i < 16; ++i) {
            float4 q4 = *reinterpret_cast<const float4*>(qp + 4 * i);
            qreg[4*i+0] = q4.x * 0.125f; qreg[4*i+1] = q4.y * 0.125f;
            qreg[4*i+2] = q4.z * 0.125f; qreg[4*i+3] = q4.w * 0.125f;
        }
    }

    float acc[16];
    #pragma unroll
    for (int j = 0; j < 16; ++j) acc[j] = 0.f;
    float mrow = -1e30f, lrow = 0.f;

    for (int kt = 0; kt <= qt; ++kt) {
        __syncthreads();  // previous tile fully consumed
        {
            const float* kb = qkv + ((size_t)(b * SEQ + kt * 64 + r)) * NQKV + 512  + kv * 64 + cs;
            const float* vb = qkv + ((size_t)(b * SEQ + kt * 64 + r)) * NQKV + 1024 + kv * 64 + cs;
            #pragma unroll
            for (int i = 0; i < 4; ++i) {
                *reinterpret_cast<float4*>(&Kx[r][cs + 4 * i]) = *reinterpret_cast<const float4*>(kb + 4 * i);
                *reinterpret_cast<float4*>(&Vx[r][cs + 4 * i]) = *reinterpret_cast<const float4*>(vb + 4 * i);
            }
        }
        __syncthreads();

        // scores for this thread's 16 columns
        float s[16];
        float tmax = -1e30f;
        #pragma unroll
        for (int cc = 0; cc < 16; ++cc) {
            const int c = cs + cc;
            float dot = 0.f;
            #pragma unroll
            for (int i = 0; i < 16; ++i) {
                float4 k4 = *reinterpret_cast<const float4*>(&Kx[c][4 * i]);
                dot = fmaf(qreg[4*i+0], k4.x, dot);
                dot = fmaf(qreg[4*i+1], k4.y, dot);
                dot = fmaf(qreg[4*i+2], k4.z, dot);
                dot = fmaf(qreg[4*i+3], k4.w, dot);
            }
            const bool valid = (kt * 64 + c) <= q_glob;
            s[cc] = valid ? dot : -1e30f;
            tmax = fmaxf(tmax, s[cc]);
        }
        // row max across the 4 threads of this row (consecutive lanes)
        tmax = fmaxf(tmax, __shfl_xor(tmax, 1));
        tmax = fmaxf(tmax, __shfl_xor(tmax, 2));
        const float mnew  = fmaxf(mrow, tmax);
        const float alpha = __expf(mrow - mnew);
        float psum = 0.f;
        #pragma unroll
        for (int cc = 0; cc < 16; ++cc) {
            const float p = __expf(s[cc] - mnew);
            P[r][cs + cc] = p;
            psum += p;
        }
        psum += __shfl_xor(psum, 1);
        psum += __shfl_xor(psum, 2);
        lrow = lrow * alpha + psum;
        mrow = mnew;
        #pragma unroll
        for (int j = 0; j < 16; ++j) acc[j] *= alpha;
        __syncthreads();  // P visible

        // acc += P[r][:] @ V[:, cs..cs+15]
        for (int kk = 0; kk < 64; ++kk) {
            const float p = P[r][kk];
            float4 v0 = *reinterpret_cast<const float4*>(&Vx[kk][cs]);
            float4 v1 = *reinterpret_cast<const float4*>(&Vx[kk][cs + 4]);
            float4 v2 = *reinterpret_cast<const float4*>(&Vx[kk][cs + 8]);
            float4 v3 = *reinterpret_cast<const float4*>(&Vx[kk][cs + 12]);
            acc[0]  = fmaf(p, v0.x, acc[0]);  acc[1]  = fmaf(p, v0.y, acc[1]);
            acc[2]  = fmaf(p, v0.z, acc[2]);  acc[3]  = fmaf(p, v0.w, acc[3]);
            acc[4]  = fmaf(p, v1.x, acc[4]);  acc[5]  = fmaf(p, v1.y, acc[5]);
            acc[6]  = fmaf(p, v1.z, acc[6]);  acc[7]  = fmaf(p, v1.w, acc[7]);
            acc[8]  = fmaf(p, v2.x, acc[8]);  acc[9]  = fmaf(p, v2.y, acc[9]);
            acc[10] = fmaf(p, v2.z, acc[10]); acc[11] = fmaf(p, v2.w, acc[11]);
            acc[12] = fmaf(p, v3.x, acc[12]); acc[13] = fmaf(p, v3.y, acc[13]);
            acc[14] = fmaf(p, v3.z, acc[14]); acc[15] = fmaf(p, v3.w, acc[15]);
        }
    }

    const float inv = 1.f / lrow;
    bf16* zp = z + ((size_t)(b * SEQ + qt * 64 + r)) * (NKV * DHEAD) + kv * 64 + cs;
    #pragma unroll
    for (int j = 0; j < 16; ++j) zp[j] = __float2bfloat16(acc[j] * inv);
}

// ---------------------------------------------------------------------------
// launch
// ---------------------------------------------------------------------------
extern "C" void kernel_launch(void* const* d_in, const int* in_sizes, int n_in,
                              void* d_out, int out_size, void* d_ws, size_t ws_size,
                              hipStream_t stream)
{
    const float* resid_pre = (const float*)d_in[0];
    const float* W_Q   = (const float*)d_in[1];
    const float* W_K   = (const float*)d_in[2];
    const float* W_V   = (const float*)d_in[3];
    const float* W_O   = (const float*)d_in[4];   // [8][64][2048] == [512][2048]
    const float* g1    = (const float*)d_in[5];
    const float* b1    = (const float*)d_in[6];
    const float* g2    = (const float*)d_in[7];
    const float* b2    = (const float*)d_in[8];
    const float* W_in  = (const float*)d_in[9];
    const float* b_in  = (const float*)d_in[10];
    const float* W_out = (const float*)d_in[11];
    const float* b_out = (const float*)d_in[12];
    float* out = (float*)d_out;

    char* ws = (char*)d_ws;
    // workspace layout (bytes)
    const size_t OFF_WQKV = 0;                                  // 12,582,912
    const size_t OFF_X1   = OFF_WQKV + (size_t)D_MODEL * NQKV * 4;      // x1 & x2 (reused)
    const size_t OFF_QKV  = OFF_X1   + (size_t)NTOK * D_MODEL * 2;
    const size_t OFF_Z    = OFF_QKV  + (size_t)NTOK * NQKV * 4;
    const size_t OFF_RMID = OFF_Z    + (size_t)NTOK * NKV * DHEAD * 2;
    const size_t OFF_POST = OFF_RMID + (size_t)NTOK * D_MODEL * 4;
    // total = OFF_POST + 4096*8192*2 = ~152 MiB

    float* wqkv      = (float*)(ws + OFF_WQKV);
    bf16*  x1        = (bf16*) (ws + OFF_X1);
    float* qkv       = (float*)(ws + OFF_QKV);
    bf16*  zbuf      = (bf16*) (ws + OFF_Z);
    float* resid_mid = (float*)(ws + OFF_RMID);
    bf16*  post      = (bf16*) (ws + OFF_POST);

    // 1. combined QKV weight (group-summed Q)
    build_wqkv_kernel<<<(D_MODEL * NQKV + 255) / 256, 256, 0, stream>>>(W_Q, W_K, W_V, wqkv);
    // 2. x1 = rmsnorm(resid_pre)
    rmsnorm_kernel<<<NTOK, 256, 0, stream>>>(resid_pre, g1, b1, x1);
    // 3. qkv = x1 @ wqkv           [4096 x 1536], K=2048
    gemm_kernel<float, false, false, false><<<dim3(NQKV / 128, NTOK / 128), 256, 0, stream>>>(
        x1, wqkv, qkv, nullptr, nullptr, NTOK, NQKV, D_MODEL);
    // 4. z = attention(qkv)        bf16 [4096 x 512]
    attn_kernel<<<dim3(SEQ / 64, NKV, NB), 256, 0, stream>>>(qkv, zbuf);
    // 5. resid_mid = z @ W_O + resid_pre    [4096 x 2048], K=512
    gemm_kernel<float, false, false, true><<<dim3(D_MODEL / 128, NTOK / 128), 256, 0, stream>>>(
        zbuf, W_O, resid_mid, nullptr, resid_pre, NTOK, D_MODEL, NKV * DHEAD);
    // 6. x2 = rmsnorm(resid_mid)   (reuses x1 buffer)
    rmsnorm_kernel<<<NTOK, 256, 0, stream>>>(resid_mid, g2, b2, x1);
    // 7. post = relu(x2 @ W_in + b_in)   bf16 [4096 x 8192], K=2048
    gemm_kernel<bf16, true, true, false><<<dim3(DMLP / 128, NTOK / 128), 256, 0, stream>>>(
        x1, W_in, post, b_in, nullptr, NTOK, DMLP, D_MODEL);
    // 8. out = post @ W_out + b_out + resid_mid   [4096 x 2048], K=8192
    gemm_kernel<float, true, false, true><<<dim3(D_MODEL / 128, NTOK / 128), 256, 0, stream>>>(
        post, W_out, out, b_out, resid_mid, NTOK, D_MODEL, DMLP);
}

// Round 2
// 1152.626 us; speedup vs baseline: 4.1395x; 4.1395x over previous
//
#include <hip/hip_runtime.h>
#include <hip/hip_bf16.h>

// ---------------------------------------------------------------------------
// TransformerBlock forward, MI355X (gfx950).
// B=2, S=2048, D=2048, HQ=32 (group-summed into 8), HKV=8, DH=64, DMLP=8192.
// Round-2: all GEMMs on MFMA (bf16 16x16x32, m97 structure: 128x128 tile,
// BK=32, global_load_lds width=16). Weights pre-transposed to bf16 [N][K].
// Attention remains vector flash (next round's target).
// ---------------------------------------------------------------------------

using bf16 = __hip_bfloat16;
typedef __bf16 bf16x8_t __attribute__((ext_vector_type(8)));
typedef float  f32x4_t  __attribute__((ext_vector_type(4)));

#define D_MODEL 2048
#define SEQ     2048
#define NB      2
#define NTOK    4096
#define NKV     8
#define DHEAD   64
#define DMLP    8192
#define NQKV    1536

__device__ inline void storev(float* p, float v) { *p = v; }
__device__ inline void storev(bf16* p, float v)  { *p = __float2bfloat16(v); }

// ---------------------------------------------------------------------------
// Tiled transpose + f32->bf16: in [K][N] f32  ->  out [N][K] bf16.
// grid (N/32, K/32), 256 threads.
// ---------------------------------------------------------------------------
__global__ __launch_bounds__(256) void transpose_f32_bf16_kernel(
    const float* __restrict__ in, bf16* __restrict__ out, int K, int N)
{
    __shared__ float tile[32][33];
    const int n0 = blockIdx.x * 32, k0 = blockIdx.y * 32;
    const int tx = threadIdx.x & 31, ty = threadIdx.x >> 5;   // ty 0..7
    #pragma unroll
    for (int i = 0; i < 32; i += 8)
        tile[ty + i][tx] = in[(size_t)(k0 + ty + i) * N + n0 + tx];
    __syncthreads();
    #pragma unroll
    for (int i = 0; i < 32; i += 8)
        out[(size_t)(n0 + ty + i) * K + k0 + tx] = __float2bfloat16(tile[tx][ty + i]);
}

// ---------------------------------------------------------------------------
// Head-major weight transpose with optional group sum:
// in [NKV*ngroup][2048][64] f32 -> out rows (kv*64+e) x cols k (2048) bf16,
// out[kv*64+e][k] = sum_g in[kv*ngroup+g][k][e].  grid (2048/32, NKV).
// ---------------------------------------------------------------------------
__global__ __launch_bounds__(256) void head_transpose_kernel(
    const float* __restrict__ in, bf16* __restrict__ out, int ngroup)
{
    __shared__ float tile[32][65];      // [k][e]
    const int kv = blockIdx.y;
    const int k0 = blockIdx.x * 32;
    const int t  = threadIdx.x;
    const int e  = t & 63, kk = t >> 6;      // 4 k-rows per pass
    #pragma unroll
    for (int i = 0; i < 32; i += 4) {
        float s = 0.f;
        for (int g = 0; g < ngroup; ++g)
            s += in[((size_t)(kv * ngroup + g) * 2048 + k0 + kk + i) * 64 + e];
        tile[kk + i][e] = s;
    }
    __syncthreads();
    const int k = t & 31, ee = t >> 5;       // 8 e-rows per pass
    #pragma unroll
    for (int i = 0; i < 64; i += 8)
        out[(size_t)(kv * 64 + ee + i) * 2048 + k0 + k] = __float2bfloat16(tile[k][ee + i]);
}

// ---------------------------------------------------------------------------
// RMSNorm (faithful: x / sqrt(var(x)+eps) * g + b, mean only inside var).
// ---------------------------------------------------------------------------
__global__ __launch_bounds__(256) void rmsnorm_kernel(
    const float* __restrict__ x, const float* __restrict__ g,
    const float* __restrict__ b, bf16* __restrict__ out)
{
    const int row = blockIdx.x;
    const int t = threadIdx.x;
    const float* xr = x + (size_t)row * D_MODEL;
    float4 a0 = *reinterpret_cast<const float4*>(xr + t * 8);
    float4 a1 = *reinterpret_cast<const float4*>(xr + t * 8 + 4);
    float v[8] = {a0.x, a0.y, a0.z, a0.w, a1.x, a1.y, a1.z, a1.w};
    float sum = 0.f, sumsq = 0.f;
    #pragma unroll
    for (int j = 0; j < 8; ++j) { sum += v[j]; sumsq += v[j] * v[j]; }
    #pragma unroll
    for (int o = 1; o < 64; o <<= 1) {
        sum   += __shfl_xor(sum, o);
        sumsq += __shfl_xor(sumsq, o);
    }
    __shared__ float rs[4], rq[4];
    if ((t & 63) == 0) { rs[t >> 6] = sum; rq[t >> 6] = sumsq; }
    __syncthreads();
    sum   = rs[0] + rs[1] + rs[2] + rs[3];
    sumsq = rq[0] + rq[1] + rq[2] + rq[3];
    const float mu  = sum * (1.f / D_MODEL);
    const float var = sumsq * (1.f / D_MODEL) - mu * mu;
    const float rstd = 1.f / sqrtf(var + 1e-5f);
    const int c = t * 8;
    float4 g0 = *reinterpret_cast<const float4*>(g + c);
    float4 g1 = *reinterpret_cast<const float4*>(g + c + 4);
    float4 b0 = *reinterpret_cast<const float4*>(b + c);
    float4 b1 = *reinterpret_cast<const float4*>(b + c + 4);
    float gg[8] = {g0.x, g0.y, g0.z, g0.w, g1.x, g1.y, g1.z, g1.w};
    float bb[8] = {b0.x, b0.y, b0.z, b0.w, b1.x, b1.y, b1.z, b1.w};
    bf16* op = out + (size_t)row * D_MODEL + c;
    #pragma unroll
    for (int j = 0; j < 8; ++j) op[j] = __float2bfloat16(v[j] * rstd * gg[j] + bb[j]);
}

// ---------------------------------------------------------------------------
// MFMA GEMM: C[M][N] = A[M][K](bf16) * Bt[N][K](bf16)^T (+bias)(relu)(+resid)
// m97 structure: 128x128 tile, BK=32, 4 waves, 4x4 16x16x32 fragments each.
// ---------------------------------------------------------------------------
template<typename TC, bool BIAS, bool RELU, bool RESID>
__global__ __launch_bounds__(256) void mfma_gemm_kernel(
    const bf16* __restrict__ A, const bf16* __restrict__ Bt,
    TC* __restrict__ C, const float* __restrict__ bias,
    const float* __restrict__ resid, int M, int N, int K)
{
    __shared__ __align__(16) bf16 As[128 * 32];
    __shared__ __align__(16) bf16 Bs[128 * 32];
    const int t  = threadIdx.x;
    const int wv = t >> 6, ln = t & 63;
    const int row0 = blockIdx.y * 128, col0 = blockIdx.x * 128;
    const int wr = (wv >> 1) * 64, wc = (wv & 1) * 64;   // wave output origin
    const int lr = ln & 15;                              // fragment row/col
    const int lk = (ln >> 4) * 8;                        // fragment k offset

    f32x4_t acc[4][4];
    #pragma unroll
    for (int i = 0; i < 4; ++i)
        #pragma unroll
        for (int j = 0; j < 4; ++j) acc[i][j] = (f32x4_t){0.f, 0.f, 0.f, 0.f};

    // staging geometry: element idx = chunk*2048 + wv*512 + ln*8 in [row][32]
    const int sidx = wv * 512 + ln * 8;
    const int sr = sidx >> 5;          // 0..63
    const int sc = sidx & 31;
    const bf16* gA0 = A  + (size_t)(row0 + sr)      * K + sc;
    const bf16* gA1 = A  + (size_t)(row0 + sr + 64) * K + sc;
    const bf16* gB0 = Bt + (size_t)(col0 + sr)      * K + sc;
    const bf16* gB1 = Bt + (size_t)(col0 + sr + 64) * K + sc;
    bf16* lA0 = As + wv * 512;
    bf16* lA1 = As + 2048 + wv * 512;
    bf16* lB0 = Bs + wv * 512;
    bf16* lB1 = Bs + 2048 + wv * 512;

    for (int kt = 0; kt < K; kt += 32) {
        __builtin_amdgcn_global_load_lds(
            (const __attribute__((address_space(1))) void*)(gA0 + kt),
            (__attribute__((address_space(3))) void*)lA0, 16, 0, 0);
        __builtin_amdgcn_global_load_lds(
            (const __attribute__((address_space(1))) void*)(gA1 + kt),
            (__attribute__((address_space(3))) void*)lA1, 16, 0, 0);
        __builtin_amdgcn_global_load_lds(
            (const __attribute__((address_space(1))) void*)(gB0 + kt),
            (__attribute__((address_space(3))) void*)lB0, 16, 0, 0);
        __builtin_amdgcn_global_load_lds(
            (const __attribute__((address_space(1))) void*)(gB1 + kt),
            (__attribute__((address_space(3))) void*)lB1, 16, 0, 0);
        __syncthreads();   // drains vmcnt -> tiles resident

        bf16x8_t af[4], bfr[4];
        #pragma unroll
        for (int m = 0; m < 4; ++m)
            af[m] = *reinterpret_cast<const bf16x8_t*>(&As[(wr + m * 16 + lr) * 32 + lk]);
        #pragma unroll
        for (int n = 0; n < 4; ++n)
            bfr[n] = *reinterpret_cast<const bf16x8_t*>(&Bs[(wc + n * 16 + lr) * 32 + lk]);
        #pragma unroll
        for (int m = 0; m < 4; ++m)
            #pragma unroll
            for (int n = 0; n < 4; ++n)
                acc[m][n] = __builtin_amdgcn_mfma_f32_16x16x32_bf16(af[m], bfr[n], acc[m][n], 0, 0, 0);
        __syncthreads();   // LDS reads done before next stage overwrites
    }

    // epilogue: C/D layout col=lane&15, row=(lane>>4)*4+j   [verified m89/m91]
    #pragma unroll
    for (int m = 0; m < 4; ++m) {
        #pragma unroll
        for (int n = 0; n < 4; ++n) {
            const int c = col0 + wc + n * 16 + lr;
            #pragma unroll
            for (int j = 0; j < 4; ++j) {
                const int r = row0 + wr + m * 16 + (ln >> 4) * 4 + j;
                float v = acc[m][n][j];
                if constexpr (BIAS)  v += bias[c];
                if constexpr (RELU)  v = fmaxf(v, 0.f);
                if constexpr (RESID) v += resid[(size_t)r * N + c];
                storev(&C[(size_t)r * N + c], v);
            }
        }
    }
}

// ---------------------------------------------------------------------------
// Flash attention (vector, round-1 verified). qkv f32 [NTOK][1536]:
// q 0..511 (group-summed), k 512.., v 1024.. ; z out bf16 [NTOK][512].
// ---------------------------------------------------------------------------
__global__ __launch_bounds__(256) void attn_kernel(
    const float* __restrict__ qkv, bf16* __restrict__ z)
{
    const int qt = blockIdx.x;
    const int kv = blockIdx.y;
    const int b  = blockIdx.z;
    const int t  = threadIdx.x;
    const int r  = t >> 2;
    const int cs = (t & 3) * 16;

    __shared__ float Kx[64][68];
    __shared__ float Vx[64][68];
    __shared__ float P [64][68];

    const int q_glob = qt * 64 + r;

    float qreg[64];
    {
        const float* qp = qkv + ((size_t)(b * SEQ + qt * 64 + r)) * NQKV + kv * 64;
        #pragma unroll
        for (int i = 0; i < 16; ++i) {
            float4 q4 = *reinterpret_cast<const float4*>(qp + 4 * i);
            qreg[4*i+0] = q4.x * 0.125f; qreg[4*i+1] = q4.y * 0.125f;
            qreg[4*i+2] = q4.z * 0.125f; qreg[4*i+3] = q4.w * 0.125f;
        }
    }

    float acc[16];
    #pragma unroll
    for (int j = 0; j < 16; ++j) acc[j] = 0.f;
    float mrow = -1e30f, lrow = 0.f;

    for (int kt = 0; kt <= qt; ++kt) {
        __syncthreads();
        {
            const float* kb = qkv + ((size_t)(b * SEQ + kt * 64 + r)) * NQKV + 512  + kv * 64 + cs;
            const float* vb = qkv + ((size_t)(b * SEQ + kt * 64 + r)) * NQKV + 1024 + kv * 64 + cs;
            #pragma unroll
            for (int i = 0; i < 4; ++i) {
                *reinterpret_cast<float4*>(&Kx[r][cs + 4 * i]) = *reinterpret_cast<const float4*>(kb + 4 * i);
                *reinterpret_cast<float4*>(&Vx[r][cs + 4 * i]) = *reinterpret_cast<const float4*>(vb + 4 * i);
            }
        }
        __syncthreads();

        float s[16];
        float tmax = -1e30f;
        #pragma unroll
        for (int cc = 0; cc < 16; ++cc) {
            const int c = cs + cc;
            float dot = 0.f;
            #pragma unroll
            for (int i = 0; i < 16; ++i) {
                float4 k4 = *reinterpret_cast<const float4*>(&Kx[c][4 * i]);
                dot = fmaf(qreg[4*i+0], k4.x, dot);
                dot = fmaf(qreg[4*i+1], k4.y, dot);
                dot = fmaf(qreg[4*i+2], k4.z, dot);
                dot = fmaf(qreg[4*i+3], k4.w, dot);
            }
            const bool valid = (kt * 64 + c) <= q_glob;
            s[cc] = valid ? dot : -1e30f;
            tmax = fmaxf(tmax, s[cc]);
        }
        tmax = fmaxf(tmax, __shfl_xor(tmax, 1));
        tmax = fmaxf(tmax, __shfl_xor(tmax, 2));
        const float mnew  = fmaxf(mrow, tmax);
        const float alpha = __expf(mrow - mnew);
        float psum = 0.f;
        #pragma unroll
        for (int cc = 0; cc < 16; ++cc) {
            const float p = __expf(s[cc] - mnew);
            P[r][cs + cc] = p;
            psum += p;
        }
        psum += __shfl_xor(psum, 1);
        psum += __shfl_xor(psum, 2);
        lrow = lrow * alpha + psum;
        mrow = mnew;
        #pragma unroll
        for (int j = 0; j < 16; ++j) acc[j] *= alpha;
        __syncthreads();

        for (int kk = 0; kk < 64; ++kk) {
            const float p = P[r][kk];
            float4 v0 = *reinterpret_cast<const float4*>(&Vx[kk][cs]);
            float4 v1 = *reinterpret_cast<const float4*>(&Vx[kk][cs + 4]);
            float4 v2 = *reinterpret_cast<const float4*>(&Vx[kk][cs + 8]);
            float4 v3 = *reinterpret_cast<const float4*>(&Vx[kk][cs + 12]);
            acc[0]  = fmaf(p, v0.x, acc[0]);  acc[1]  = fmaf(p, v0.y, acc[1]);
            acc[2]  = fmaf(p, v0.z, acc[2]);  acc[3]  = fmaf(p, v0.w, acc[3]);
            acc[4]  = fmaf(p, v1.x, acc[4]);  acc[5]  = fmaf(p, v1.y, acc[5]);
            acc[6]  = fmaf(p, v1.z, acc[6]);  acc[7]  = fmaf(p, v1.w, acc[7]);
            acc[8]  = fmaf(p, v2.x, acc[8]);  acc[9]  = fmaf(p, v2.y, acc[9]);
            acc[10] = fmaf(p, v2.z, acc[10]); acc[11] = fmaf(p, v2.w, acc[11]);
            acc[12] = fmaf(p, v3.x, acc[12]); acc[13] = fmaf(p, v3.y, acc[13]);
            acc[14] = fmaf(p, v3.z, acc[14]); acc[15] = fmaf(p, v3.w, acc[15]);
        }
    }

    const float inv = 1.f / lrow;
    bf16* zp = z + ((size_t)(b * SEQ + qt * 64 + r)) * (NKV * DHEAD) + kv * 64 + cs;
    #pragma unroll
    for (int j = 0; j < 16; ++j) zp[j] = __float2bfloat16(acc[j] * inv);
}

// ---------------------------------------------------------------------------
// launch
// ---------------------------------------------------------------------------
extern "C" void kernel_launch(void* const* d_in, const int* in_sizes, int n_in,
                              void* d_out, int out_size, void* d_ws, size_t ws_size,
                              hipStream_t stream)
{
    const float* resid_pre = (const float*)d_in[0];
    const float* W_Q   = (const float*)d_in[1];
    const float* W_K   = (const float*)d_in[2];
    const float* W_V   = (const float*)d_in[3];
    const float* W_O   = (const float*)d_in[4];
    const float* g1    = (const float*)d_in[5];
    const float* b1    = (const float*)d_in[6];
    const float* g2    = (const float*)d_in[7];
    const float* b2    = (const float*)d_in[8];
    const float* W_in  = (const float*)d_in[9];
    const float* b_in  = (const float*)d_in[10];
    const float* W_out = (const float*)d_in[11];
    const float* b_out = (const float*)d_in[12];
    float* out = (float*)d_out;

    char* ws = (char*)d_ws;
    // layout (bytes), total ~153 MB (< round-1's 159 MB proven footprint):
    const size_t OFF_WBIG  = 0;                                    // winT, later woutT [33.5M]
    const size_t OFF_WOT   = OFF_WBIG + (size_t)DMLP * D_MODEL * 2;        // woT  [2.1M]
    const size_t OFF_X1    = OFF_WOT  + (size_t)D_MODEL * 512 * 2;         // x1/x2 bf16 [16.8M]
    const size_t OFF_RMID  = OFF_X1   + (size_t)NTOK * D_MODEL * 2;        // resid_mid f32 [33.5M]
    const size_t OFF_POST  = OFF_RMID + (size_t)NTOK * D_MODEL * 4;        // post bf16 [67.1M]
    // aliased INSIDE post region (all dead before post is written):
    const size_t OFF_WQKVT = OFF_POST;                                     // wqkvT bf16 [6.3M]
    const size_t OFF_QKV   = OFF_WQKVT + (size_t)NQKV * D_MODEL * 2;       // qkv f32 [25.2M]
    const size_t OFF_Z     = OFF_QKV   + (size_t)NTOK * NQKV * 4;          // z bf16 [4.2M]

    bf16*  winT   = (bf16*) (ws + OFF_WBIG);
    bf16*  woutT  = (bf16*) (ws + OFF_WBIG);
    bf16*  woT    = (bf16*) (ws + OFF_WOT);
    bf16*  x1     = (bf16*) (ws + OFF_X1);
    float* rmid   = (float*)(ws + OFF_RMID);
    bf16*  post   = (bf16*) (ws + OFF_POST);
    bf16*  wqkvT  = (bf16*) (ws + OFF_WQKVT);
    float* qkv    = (float*)(ws + OFF_QKV);
    bf16*  zbuf   = (bf16*) (ws + OFF_Z);

    // --- weight prep ---
    // winT [8192][2048] <- W_in [2048][8192]
    transpose_f32_bf16_kernel<<<dim3(DMLP / 32, D_MODEL / 32), 256, 0, stream>>>(W_in, winT, D_MODEL, DMLP);
    // wqkvT [1536][2048]: rows 0..511 group-summed Q, 512..1023 K, 1024..1535 V
    head_transpose_kernel<<<dim3(D_MODEL / 32, NKV), 256, 0, stream>>>(W_Q, wqkvT, 4);
    head_transpose_kernel<<<dim3(D_MODEL / 32, NKV), 256, 0, stream>>>(W_K, wqkvT + (size_t)512  * D_MODEL, 1);
    head_transpose_kernel<<<dim3(D_MODEL / 32, NKV), 256, 0, stream>>>(W_V, wqkvT + (size_t)1024 * D_MODEL, 1);
    // woT [2048][512] <- W_O [512][2048]
    transpose_f32_bf16_kernel<<<dim3(D_MODEL / 32, 512 / 32), 256, 0, stream>>>(W_O, woT, 512, D_MODEL);

    // --- block ---
    // x1 = rmsnorm(resid_pre)
    rmsnorm_kernel<<<NTOK, 256, 0, stream>>>(resid_pre, g1, b1, x1);
    // qkv = x1 @ wqkvT^T   [4096 x 1536], K=2048
    mfma_gemm_kernel<float, false, false, false><<<dim3(NQKV / 128, NTOK / 128), 256, 0, stream>>>(
        x1, wqkvT, qkv, nullptr, nullptr, NTOK, NQKV, D_MODEL);
    // z = attention(qkv)
    attn_kernel<<<dim3(SEQ / 64, NKV, NB), 256, 0, stream>>>(qkv, zbuf);
    // rmid = z @ woT^T + resid_pre   [4096 x 2048], K=512
    mfma_gemm_kernel<float, false, false, true><<<dim3(D_MODEL / 128, NTOK / 128), 256, 0, stream>>>(
        zbuf, woT, rmid, nullptr, resid_pre, NTOK, D_MODEL, 512);
    // x2 = rmsnorm(rmid) (reuse x1)
    rmsnorm_kernel<<<NTOK, 256, 0, stream>>>(rmid, g2, b2, x1);
    // post = relu(x2 @ winT^T + b_in)   [4096 x 8192], K=2048  (overwrites alias region)
    mfma_gemm_kernel<bf16, true, true, false><<<dim3(DMLP / 128, NTOK / 128), 256, 0, stream>>>(
        x1, winT, post, b_in, nullptr, NTOK, DMLP, D_MODEL);
    // woutT [2048][8192] <- W_out [8192][2048]  (winT dead now; reuse region)
    transpose_f32_bf16_kernel<<<dim3(D_MODEL / 32, DMLP / 32), 256, 0, stream>>>(W_out, woutT, DMLP, D_MODEL);
    // out = post @ woutT^T + b_out + rmid   [4096 x 2048], K=8192
    mfma_gemm_kernel<float, true, false, true><<<dim3(D_MODEL / 128, NTOK / 128), 256, 0, stream>>>(
        post, woutT, out, b_out, rmid, NTOK, D_MODEL, DMLP);
}

// Round 3
// 638.051 us; speedup vs baseline: 7.4779x; 1.8065x over previous
//
#include <hip/hip_runtime.h>
#include <hip/hip_bf16.h>

// ---------------------------------------------------------------------------
// TransformerBlock forward, MI355X (gfx950).
// B=2, S=2048, D=2048, HQ=32 (group-summed into 8), HKV=8, DH=64, DMLP=8192.
// Round-3: MFMA flash attention (16x16x32 bf16) replacing vector attention.
// GEMMs keep the round-2 verified m97 structure.
// ---------------------------------------------------------------------------

using bf16 = __hip_bfloat16;
typedef __bf16 bf16x8_t __attribute__((ext_vector_type(8)));
typedef float  f32x4_t  __attribute__((ext_vector_type(4)));

#define D_MODEL 2048
#define SEQ     2048
#define NB      2
#define NTOK    4096
#define NKV     8
#define DHEAD   64
#define DMLP    8192
#define NQKV    1536

__device__ inline void storev(float* p, float v) { *p = v; }
__device__ inline void storev(bf16* p, float v)  { *p = __float2bfloat16(v); }

__device__ inline __bf16 tobf(float x) {
    union { __hip_bfloat16 h; __bf16 b; } u;
    u.h = __float2bfloat16(x);
    return u.b;
}

// ---------------------------------------------------------------------------
// Tiled transpose + f32->bf16: in [K][N] f32  ->  out [N][K] bf16.
// ---------------------------------------------------------------------------
__global__ __launch_bounds__(256) void transpose_f32_bf16_kernel(
    const float* __restrict__ in, bf16* __restrict__ out, int K, int N)
{
    __shared__ float tile[32][33];
    const int n0 = blockIdx.x * 32, k0 = blockIdx.y * 32;
    const int tx = threadIdx.x & 31, ty = threadIdx.x >> 5;
    #pragma unroll
    for (int i = 0; i < 32; i += 8)
        tile[ty + i][tx] = in[(size_t)(k0 + ty + i) * N + n0 + tx];
    __syncthreads();
    #pragma unroll
    for (int i = 0; i < 32; i += 8)
        out[(size_t)(n0 + ty + i) * K + k0 + tx] = __float2bfloat16(tile[tx][ty + i]);
}

// ---------------------------------------------------------------------------
// Head-major weight transpose with optional group sum:
// out[kv*64+e][k] = sum_g in[kv*ngroup+g][k][e].
// ---------------------------------------------------------------------------
__global__ __launch_bounds__(256) void head_transpose_kernel(
    const float* __restrict__ in, bf16* __restrict__ out, int ngroup)
{
    __shared__ float tile[32][65];
    const int kv = blockIdx.y;
    const int k0 = blockIdx.x * 32;
    const int t  = threadIdx.x;
    const int e  = t & 63, kk = t >> 6;
    #pragma unroll
    for (int i = 0; i < 32; i += 4) {
        float s = 0.f;
        for (int g = 0; g < ngroup; ++g)
            s += in[((size_t)(kv * ngroup + g) * 2048 + k0 + kk + i) * 64 + e];
        tile[kk + i][e] = s;
    }
    __syncthreads();
    const int k = t & 31, ee = t >> 5;
    #pragma unroll
    for (int i = 0; i < 64; i += 8)
        out[(size_t)(kv * 64 + ee + i) * 2048 + k0 + k] = __float2bfloat16(tile[k][ee + i]);
}

// ---------------------------------------------------------------------------
// RMSNorm (faithful: x / sqrt(var(x)+eps) * g + b).
// ---------------------------------------------------------------------------
__global__ __launch_bounds__(256) void rmsnorm_kernel(
    const float* __restrict__ x, const float* __restrict__ g,
    const float* __restrict__ b, bf16* __restrict__ out)
{
    const int row = blockIdx.x;
    const int t = threadIdx.x;
    const float* xr = x + (size_t)row * D_MODEL;
    float4 a0 = *reinterpret_cast<const float4*>(xr + t * 8);
    float4 a1 = *reinterpret_cast<const float4*>(xr + t * 8 + 4);
    float v[8] = {a0.x, a0.y, a0.z, a0.w, a1.x, a1.y, a1.z, a1.w};
    float sum = 0.f, sumsq = 0.f;
    #pragma unroll
    for (int j = 0; j < 8; ++j) { sum += v[j]; sumsq += v[j] * v[j]; }
    #pragma unroll
    for (int o = 1; o < 64; o <<= 1) {
        sum   += __shfl_xor(sum, o);
        sumsq += __shfl_xor(sumsq, o);
    }
    __shared__ float rs[4], rq[4];
    if ((t & 63) == 0) { rs[t >> 6] = sum; rq[t >> 6] = sumsq; }
    __syncthreads();
    sum   = rs[0] + rs[1] + rs[2] + rs[3];
    sumsq = rq[0] + rq[1] + rq[2] + rq[3];
    const float mu  = sum * (1.f / D_MODEL);
    const float var = sumsq * (1.f / D_MODEL) - mu * mu;
    const float rstd = 1.f / sqrtf(var + 1e-5f);
    const int c = t * 8;
    float4 g0 = *reinterpret_cast<const float4*>(g + c);
    float4 g1 = *reinterpret_cast<const float4*>(g + c + 4);
    float4 b0 = *reinterpret_cast<const float4*>(b + c);
    float4 b1 = *reinterpret_cast<const float4*>(b + c + 4);
    float gg[8] = {g0.x, g0.y, g0.z, g0.w, g1.x, g1.y, g1.z, g1.w};
    float bb[8] = {b0.x, b0.y, b0.z, b0.w, b1.x, b1.y, b1.z, b1.w};
    bf16* op = out + (size_t)row * D_MODEL + c;
    #pragma unroll
    for (int j = 0; j < 8; ++j) op[j] = __float2bfloat16(v[j] * rstd * gg[j] + bb[j]);
}

// ---------------------------------------------------------------------------
// MFMA GEMM (round-2 verified): C = A[M][K] * Bt[N][K]^T (+bias)(relu)(+resid)
// ---------------------------------------------------------------------------
template<typename TC, bool BIAS, bool RELU, bool RESID>
__global__ __launch_bounds__(256) void mfma_gemm_kernel(
    const bf16* __restrict__ A, const bf16* __restrict__ Bt,
    TC* __restrict__ C, const float* __restrict__ bias,
    const float* __restrict__ resid, int M, int N, int K)
{
    __shared__ __align__(16) bf16 As[128 * 32];
    __shared__ __align__(16) bf16 Bs[128 * 32];
    const int t  = threadIdx.x;
    const int wv = t >> 6, ln = t & 63;
    const int row0 = blockIdx.y * 128, col0 = blockIdx.x * 128;
    const int wr = (wv >> 1) * 64, wc = (wv & 1) * 64;
    const int lr = ln & 15;
    const int lk = (ln >> 4) * 8;

    f32x4_t acc[4][4];
    #pragma unroll
    for (int i = 0; i < 4; ++i)
        #pragma unroll
        for (int j = 0; j < 4; ++j) acc[i][j] = (f32x4_t){0.f, 0.f, 0.f, 0.f};

    const int sidx = wv * 512 + ln * 8;
    const int sr = sidx >> 5;
    const int sc = sidx & 31;
    const bf16* gA0 = A  + (size_t)(row0 + sr)      * K + sc;
    const bf16* gA1 = A  + (size_t)(row0 + sr + 64) * K + sc;
    const bf16* gB0 = Bt + (size_t)(col0 + sr)      * K + sc;
    const bf16* gB1 = Bt + (size_t)(col0 + sr + 64) * K + sc;
    bf16* lA0 = As + wv * 512;
    bf16* lA1 = As + 2048 + wv * 512;
    bf16* lB0 = Bs + wv * 512;
    bf16* lB1 = Bs + 2048 + wv * 512;

    for (int kt = 0; kt < K; kt += 32) {
        __builtin_amdgcn_global_load_lds(
            (const __attribute__((address_space(1))) void*)(gA0 + kt),
            (__attribute__((address_space(3))) void*)lA0, 16, 0, 0);
        __builtin_amdgcn_global_load_lds(
            (const __attribute__((address_space(1))) void*)(gA1 + kt),
            (__attribute__((address_space(3))) void*)lA1, 16, 0, 0);
        __builtin_amdgcn_global_load_lds(
            (const __attribute__((address_space(1))) void*)(gB0 + kt),
            (__attribute__((address_space(3))) void*)lB0, 16, 0, 0);
        __builtin_amdgcn_global_load_lds(
            (const __attribute__((address_space(1))) void*)(gB1 + kt),
            (__attribute__((address_space(3))) void*)lB1, 16, 0, 0);
        __syncthreads();

        bf16x8_t af[4], bfr[4];
        #pragma unroll
        for (int m = 0; m < 4; ++m)
            af[m] = *reinterpret_cast<const bf16x8_t*>(&As[(wr + m * 16 + lr) * 32 + lk]);
        #pragma unroll
        for (int n = 0; n < 4; ++n)
            bfr[n] = *reinterpret_cast<const bf16x8_t*>(&Bs[(wc + n * 16 + lr) * 32 + lk]);
        #pragma unroll
        for (int m = 0; m < 4; ++m)
            #pragma unroll
            for (int n = 0; n < 4; ++n)
                acc[m][n] = __builtin_amdgcn_mfma_f32_16x16x32_bf16(af[m], bfr[n], acc[m][n], 0, 0, 0);
        __syncthreads();
    }

    #pragma unroll
    for (int m = 0; m < 4; ++m) {
        #pragma unroll
        for (int n = 0; n < 4; ++n) {
            const int c = col0 + wc + n * 16 + lr;
            #pragma unroll
            for (int j = 0; j < 4; ++j) {
                const int r = row0 + wr + m * 16 + (ln >> 4) * 4 + j;
                float v = acc[m][n][j];
                if constexpr (BIAS)  v += bias[c];
                if constexpr (RELU)  v = fmaxf(v, 0.f);
                if constexpr (RESID) v += resid[(size_t)r * N + c];
                storev(&C[(size_t)r * N + c], v);
            }
        }
    }
}

// ---------------------------------------------------------------------------
// MFMA flash attention. qkv f32 [NTOK][1536]: q 0..511 (group-summed),
// k 512.., v 1024.. ; z out bf16 [NTOK][512] (kv-major, d inner).
// Block: 512 thr (8 waves), QBLK=128 q-rows (16/wave), KV tile = 64.
// Frag layouts as verified by mfma_gemm: A/B row=lane&15, k=(lane>>4)*8;
// C/D col=lane&15, row=(lane>>4)*4+j.
// ---------------------------------------------------------------------------
#define QBLK  128
#define KVBLK 64
#define LP    72     // LDS row pitch (bf16 elems): 144B rows, 16B aligned

__global__ __launch_bounds__(512) void mfma_attn_kernel(
    const float* __restrict__ qkv, bf16* __restrict__ z)
{
    const int qt = blockIdx.x;      // 0..15
    const int kv = blockIdx.y;      // 0..7
    const int b  = blockIdx.z;      // 0..1
    const int t  = threadIdx.x;
    const int w  = t >> 6;          // wave 0..7
    const int ln = t & 63;
    const int lr = ln & 15;
    const int hi = ln >> 4;         // 0..3
    const int lk = hi * 8;

    __shared__ __align__(16) bf16 Ks[KVBLK * LP];   // [k][d]
    __shared__ __align__(16) bf16 Vt[DHEAD * LP];   // [d][k]
    __shared__ __align__(16) bf16 Ps[QBLK * LP];    // [q][k]

    // ---- Q fragments (rows w*16+lr), pre-converted bf16, k = kk*32+lk ----
    bf16x8_t qf[2];
    {
        const int qrow = qt * QBLK + w * 16 + lr;
        const float* qp = qkv + (size_t)(b * SEQ + qrow) * NQKV + kv * 64;
        #pragma unroll
        for (int kk = 0; kk < 2; ++kk) {
            float4 x0 = *reinterpret_cast<const float4*>(qp + kk * 32 + lk);
            float4 x1 = *reinterpret_cast<const float4*>(qp + kk * 32 + lk + 4);
            bf16x8_t v;
            v[0] = tobf(x0.x); v[1] = tobf(x0.y); v[2] = tobf(x0.z); v[3] = tobf(x0.w);
            v[4] = tobf(x1.x); v[5] = tobf(x1.y); v[6] = tobf(x1.z); v[7] = tobf(x1.w);
            qf[kk] = v;
        }
    }

    f32x4_t acc_o[4];
    #pragma unroll
    for (int n = 0; n < 4; ++n) acc_o[n] = (f32x4_t){0.f, 0.f, 0.f, 0.f};
    float m_st[4] = {-1e30f, -1e30f, -1e30f, -1e30f};
    float l_st[4] = {0.f, 0.f, 0.f, 0.f};

    // C/D rows this lane owns (per j): qbase_cd + j
    const int qbase_cd = qt * QBLK + w * 16 + hi * 4;

    const int n_tiles = 2 * qt + 2;           // kt = 0 .. 2*qt+1
    for (int kt = 0; kt < n_tiles; ++kt) {
        const int k0g = kt * KVBLK;
        __syncthreads();    // previous tile's K/Vt fully consumed
        // ---- stage K [k][d] (coalesced) ----
        {
            const int r  = t >> 3;            // 0..63
            const int c8 = (t & 7) * 8;       // 0,8,...,56
            const float* kb = qkv + (size_t)(b * SEQ + k0g + r) * NQKV + 512 + kv * 64 + c8;
            float4 k0 = *reinterpret_cast<const float4*>(kb);
            float4 k1 = *reinterpret_cast<const float4*>(kb + 4);
            bf16x8_t kvv;
            kvv[0] = tobf(k0.x); kvv[1] = tobf(k0.y); kvv[2] = tobf(k0.z); kvv[3] = tobf(k0.w);
            kvv[4] = tobf(k1.x); kvv[5] = tobf(k1.y); kvv[6] = tobf(k1.z); kvv[7] = tobf(k1.w);
            *reinterpret_cast<bf16x8_t*>(&Ks[r * LP + c8]) = kvv;
        }
        // ---- stage V transposed -> Vt [d][k]; wave w owns d = w*8..w*8+7 ----
        {
            const int dv = w * 8;             // this wave's d-slice
            const float* vb = qkv + (size_t)(b * SEQ + k0g + ln) * NQKV + 1024 + kv * 64 + dv;
            float4 v0 = *reinterpret_cast<const float4*>(vb);
            float4 v1 = *reinterpret_cast<const float4*>(vb + 4);
            float vv[8] = {v0.x, v0.y, v0.z, v0.w, v1.x, v1.y, v1.z, v1.w};
            #pragma unroll
            for (int i = 0; i < 8; ++i)
                Vt[(dv + i) * LP + ln] = __float2bfloat16(vv[i]);   // 64 lanes contiguous
        }
        __syncthreads();

        // ---- S = Q K^T (scaled afterwards) ----
        f32x4_t s[4];
        #pragma unroll
        for (int n = 0; n < 4; ++n) s[n] = (f32x4_t){0.f, 0.f, 0.f, 0.f};
        #pragma unroll
        for (int kk = 0; kk < 2; ++kk) {
            #pragma unroll
            for (int n = 0; n < 4; ++n) {
                bf16x8_t kf = *reinterpret_cast<const bf16x8_t*>(&Ks[(n * 16 + lr) * LP + kk * 32 + lk]);
                s[n] = __builtin_amdgcn_mfma_f32_16x16x32_bf16(qf[kk], kf, s[n], 0, 0, 0);
            }
        }

        // ---- scale + causal mask ----
        const bool need_mask = (kt >= 2 * qt);
        #pragma unroll
        for (int n = 0; n < 4; ++n) {
            const int colg = k0g + n * 16 + lr;
            #pragma unroll
            for (int j = 0; j < 4; ++j) {
                float val = s[n][j] * 0.125f;
                if (need_mask && colg > qbase_cd + j) val = -1e30f;
                s[n][j] = val;
            }
        }

        // ---- online softmax: row max / exp / row sum ----
        float alpha[4], mnew[4];
        #pragma unroll
        for (int j = 0; j < 4; ++j) {
            float mx = fmaxf(fmaxf(s[0][j], s[1][j]), fmaxf(s[2][j], s[3][j]));
            mx = fmaxf(mx, __shfl_xor(mx, 1));
            mx = fmaxf(mx, __shfl_xor(mx, 2));
            mx = fmaxf(mx, __shfl_xor(mx, 4));
            mx = fmaxf(mx, __shfl_xor(mx, 8));
            mnew[j]  = fmaxf(m_st[j], mx);
            alpha[j] = __expf(m_st[j] - mnew[j]);
            m_st[j]  = mnew[j];
        }
        float psum[4] = {0.f, 0.f, 0.f, 0.f};
        #pragma unroll
        for (int n = 0; n < 4; ++n) {
            #pragma unroll
            for (int j = 0; j < 4; ++j) {
                float p = __expf(s[n][j] - mnew[j]);
                psum[j] += p;
                Ps[(w * 16 + hi * 4 + j) * LP + n * 16 + lr] = __float2bfloat16(p);
            }
        }
        #pragma unroll
        for (int j = 0; j < 4; ++j) {
            float ps = psum[j];
            ps += __shfl_xor(ps, 1);
            ps += __shfl_xor(ps, 2);
            ps += __shfl_xor(ps, 4);
            ps += __shfl_xor(ps, 8);
            l_st[j] = l_st[j] * alpha[j] + ps;
        }
        #pragma unroll
        for (int n = 0; n < 4; ++n)
            #pragma unroll
            for (int j = 0; j < 4; ++j)
                acc_o[n][j] *= alpha[j];

        // ---- O += P @ V  (P rows w*16+lr from LDS; within-wave dependency,
        //      compiler inserts the lgkmcnt wait; no cross-wave sharing) ----
        #pragma unroll
        for (int kk = 0; kk < 2; ++kk) {
            bf16x8_t pa = *reinterpret_cast<const bf16x8_t*>(&Ps[(w * 16 + lr) * LP + kk * 32 + lk]);
            #pragma unroll
            for (int n = 0; n < 4; ++n) {
                bf16x8_t vf = *reinterpret_cast<const bf16x8_t*>(&Vt[(n * 16 + lr) * LP + kk * 32 + lk]);
                acc_o[n] = __builtin_amdgcn_mfma_f32_16x16x32_bf16(pa, vf, acc_o[n], 0, 0, 0);
            }
        }
    }

    // ---- write O / l ----
    #pragma unroll
    for (int j = 0; j < 4; ++j) {
        const float inv = 1.f / l_st[j];
        const int tok = b * SEQ + qbase_cd + j;
        bf16* zp = z + (size_t)tok * (NKV * DHEAD) + kv * 64;
        #pragma unroll
        for (int n = 0; n < 4; ++n)
            zp[n * 16 + lr] = __float2bfloat16(acc_o[n][j] * inv);
    }
}

// ---------------------------------------------------------------------------
// launch
// ---------------------------------------------------------------------------
extern "C" void kernel_launch(void* const* d_in, const int* in_sizes, int n_in,
                              void* d_out, int out_size, void* d_ws, size_t ws_size,
                              hipStream_t stream)
{
    const float* resid_pre = (const float*)d_in[0];
    const float* W_Q   = (const float*)d_in[1];
    const float* W_K   = (const float*)d_in[2];
    const float* W_V   = (const float*)d_in[3];
    const float* W_O   = (const float*)d_in[4];
    const float* g1    = (const float*)d_in[5];
    const float* b1    = (const float*)d_in[6];
    const float* g2    = (const float*)d_in[7];
    const float* b2    = (const float*)d_in[8];
    const float* W_in  = (const float*)d_in[9];
    const float* b_in  = (const float*)d_in[10];
    const float* W_out = (const float*)d_in[11];
    const float* b_out = (const float*)d_in[12];
    float* out = (float*)d_out;

    char* ws = (char*)d_ws;
    const size_t OFF_WBIG  = 0;                                            // winT / woutT
    const size_t OFF_WOT   = OFF_WBIG + (size_t)DMLP * D_MODEL * 2;
    const size_t OFF_X1    = OFF_WOT  + (size_t)D_MODEL * 512 * 2;
    const size_t OFF_RMID  = OFF_X1   + (size_t)NTOK * D_MODEL * 2;
    const size_t OFF_POST  = OFF_RMID + (size_t)NTOK * D_MODEL * 4;
    const size_t OFF_WQKVT = OFF_POST;                                     // aliased in post
    const size_t OFF_QKV   = OFF_WQKVT + (size_t)NQKV * D_MODEL * 2;
    const size_t OFF_Z     = OFF_QKV   + (size_t)NTOK * NQKV * 4;

    bf16*  winT   = (bf16*) (ws + OFF_WBIG);
    bf16*  woutT  = (bf16*) (ws + OFF_WBIG);
    bf16*  woT    = (bf16*) (ws + OFF_WOT);
    bf16*  x1     = (bf16*) (ws + OFF_X1);
    float* rmid   = (float*)(ws + OFF_RMID);
    bf16*  post   = (bf16*) (ws + OFF_POST);
    bf16*  wqkvT  = (bf16*) (ws + OFF_WQKVT);
    float* qkv    = (float*)(ws + OFF_QKV);
    bf16*  zbuf   = (bf16*) (ws + OFF_Z);

    // weight prep
    transpose_f32_bf16_kernel<<<dim3(DMLP / 32, D_MODEL / 32), 256, 0, stream>>>(W_in, winT, D_MODEL, DMLP);
    head_transpose_kernel<<<dim3(D_MODEL / 32, NKV), 256, 0, stream>>>(W_Q, wqkvT, 4);
    head_transpose_kernel<<<dim3(D_MODEL / 32, NKV), 256, 0, stream>>>(W_K, wqkvT + (size_t)512  * D_MODEL, 1);
    head_transpose_kernel<<<dim3(D_MODEL / 32, NKV), 256, 0, stream>>>(W_V, wqkvT + (size_t)1024 * D_MODEL, 1);
    transpose_f32_bf16_kernel<<<dim3(D_MODEL / 32, 512 / 32), 256, 0, stream>>>(W_O, woT, 512, D_MODEL);

    // block
    rmsnorm_kernel<<<NTOK, 256, 0, stream>>>(resid_pre, g1, b1, x1);
    mfma_gemm_kernel<float, false, false, false><<<dim3(NQKV / 128, NTOK / 128), 256, 0, stream>>>(
        x1, wqkvT, qkv, nullptr, nullptr, NTOK, NQKV, D_MODEL);
    mfma_attn_kernel<<<dim3(SEQ / QBLK, NKV, NB), 512, 0, stream>>>(qkv, zbuf);
    mfma_gemm_kernel<float, false, false, true><<<dim3(D_MODEL / 128, NTOK / 128), 256, 0, stream>>>(
        zbuf, woT, rmid, nullptr, resid_pre, NTOK, D_MODEL, 512);
    rmsnorm_kernel<<<NTOK, 256, 0, stream>>>(rmid, g2, b2, x1);
    mfma_gemm_kernel<bf16, true, true, false><<<dim3(DMLP / 128, NTOK / 128), 256, 0, stream>>>(
        x1, winT, post, b_in, nullptr, NTOK, DMLP, D_MODEL);
    transpose_f32_bf16_kernel<<<dim3(D_MODEL / 32, DMLP / 32), 256, 0, stream>>>(W_out, woutT, DMLP, D_MODEL);
    mfma_gemm_kernel<float, true, false, true><<<dim3(D_MODEL / 128, NTOK / 128), 256, 0, stream>>>(
        post, woutT, out, b_out, rmid, NTOK, D_MODEL, DMLP);
}

// Round 4
// 561.327 us; speedup vs baseline: 8.5000x; 1.1367x over previous
//
#include <hip/hip_runtime.h>
#include <hip/hip_bf16.h>

// ---------------------------------------------------------------------------
// TransformerBlock forward, MI355X (gfx950).
// B=2, S=2048, D=2048, HQ=32 (group-summed into 8), HKV=8, DH=64, DMLP=8192.
// Round-4: GEMMs -> counted-vmcnt double-buffered pipeline (T4), LDS XOR
// swizzle via pre-swizzled global source (T2, m173/m201 pattern), bijective
// XCD swizzle (T1). FFN1 = 256x256 tile; others 128x256 for grid fill.
// ---------------------------------------------------------------------------

using bf16 = __hip_bfloat16;
typedef __bf16 bf16x8_t __attribute__((ext_vector_type(8)));
typedef float  f32x4_t  __attribute__((ext_vector_type(4)));

#define D_MODEL 2048
#define SEQ     2048
#define NB      2
#define NTOK    4096
#define NKV     8
#define DHEAD   64
#define DMLP    8192
#define NQKV    1536

__device__ inline void storev(float* p, float v) { *p = v; }
__device__ inline void storev(bf16* p, float v)  { *p = __float2bfloat16(v); }

__device__ inline __bf16 tobf(float x) {
    union { __hip_bfloat16 h; __bf16 b; } u;
    u.h = __float2bfloat16(x);
    return u.b;
}

// ---------------------------------------------------------------------------
// Tiled transpose + f32->bf16: in [K][N] f32  ->  out [N][K] bf16.
// ---------------------------------------------------------------------------
__global__ __launch_bounds__(256) void transpose_f32_bf16_kernel(
    const float* __restrict__ in, bf16* __restrict__ out, int K, int N)
{
    __shared__ float tile[32][33];
    const int n0 = blockIdx.x * 32, k0 = blockIdx.y * 32;
    const int tx = threadIdx.x & 31, ty = threadIdx.x >> 5;
    #pragma unroll
    for (int i = 0; i < 32; i += 8)
        tile[ty + i][tx] = in[(size_t)(k0 + ty + i) * N + n0 + tx];
    __syncthreads();
    #pragma unroll
    for (int i = 0; i < 32; i += 8)
        out[(size_t)(n0 + ty + i) * K + k0 + tx] = __float2bfloat16(tile[tx][ty + i]);
}

// ---------------------------------------------------------------------------
// Head-major weight transpose with optional group sum:
// out[kv*64+e][k] = sum_g in[kv*ngroup+g][k][e].
// ---------------------------------------------------------------------------
__global__ __launch_bounds__(256) void head_transpose_kernel(
    const float* __restrict__ in, bf16* __restrict__ out, int ngroup)
{
    __shared__ float tile[32][65];
    const int kv = blockIdx.y;
    const int k0 = blockIdx.x * 32;
    const int t  = threadIdx.x;
    const int e  = t & 63, kk = t >> 6;
    #pragma unroll
    for (int i = 0; i < 32; i += 4) {
        float s = 0.f;
        for (int g = 0; g < ngroup; ++g)
            s += in[((size_t)(kv * ngroup + g) * 2048 + k0 + kk + i) * 64 + e];
        tile[kk + i][e] = s;
    }
    __syncthreads();
    const int k = t & 31, ee = t >> 5;
    #pragma unroll
    for (int i = 0; i < 64; i += 8)
        out[(size_t)(kv * 64 + ee + i) * 2048 + k0 + k] = __float2bfloat16(tile[k][ee + i]);
}

// ---------------------------------------------------------------------------
// RMSNorm (faithful: x / sqrt(var(x)+eps) * g + b).
// ---------------------------------------------------------------------------
__global__ __launch_bounds__(256) void rmsnorm_kernel(
    const float* __restrict__ x, const float* __restrict__ g,
    const float* __restrict__ b, bf16* __restrict__ out)
{
    const int row = blockIdx.x;
    const int t = threadIdx.x;
    const float* xr = x + (size_t)row * D_MODEL;
    float4 a0 = *reinterpret_cast<const float4*>(xr + t * 8);
    float4 a1 = *reinterpret_cast<const float4*>(xr + t * 8 + 4);
    float v[8] = {a0.x, a0.y, a0.z, a0.w, a1.x, a1.y, a1.z, a1.w};
    float sum = 0.f, sumsq = 0.f;
    #pragma unroll
    for (int j = 0; j < 8; ++j) { sum += v[j]; sumsq += v[j] * v[j]; }
    #pragma unroll
    for (int o = 1; o < 64; o <<= 1) {
        sum   += __shfl_xor(sum, o);
        sumsq += __shfl_xor(sumsq, o);
    }
    __shared__ float rs[4], rq[4];
    if ((t & 63) == 0) { rs[t >> 6] = sum; rq[t >> 6] = sumsq; }
    __syncthreads();
    sum   = rs[0] + rs[1] + rs[2] + rs[3];
    sumsq = rq[0] + rq[1] + rq[2] + rq[3];
    const float mu  = sum * (1.f / D_MODEL);
    const float var = sumsq * (1.f / D_MODEL) - mu * mu;
    const float rstd = 1.f / sqrtf(var + 1e-5f);
    const int c = t * 8;
    float4 g0 = *reinterpret_cast<const float4*>(g + c);
    float4 g1 = *reinterpret_cast<const float4*>(g + c + 4);
    float4 b0 = *reinterpret_cast<const float4*>(b + c);
    float4 b1 = *reinterpret_cast<const float4*>(b + c + 4);
    float gg[8] = {g0.x, g0.y, g0.z, g0.w, g1.x, g1.y, g1.z, g1.w};
    float bb[8] = {b0.x, b0.y, b0.z, b0.w, b1.x, b1.y, b1.z, b1.w};
    bf16* op = out + (size_t)row * D_MODEL + c;
    #pragma unroll
    for (int j = 0; j < 8; ++j) op[j] = __float2bfloat16(v[j] * rstd * gg[j] + bb[j]);
}

// ---------------------------------------------------------------------------
// Pipelined MFMA GEMM: C[M][N] = A[M][K](bf16) * Bt[N][K]^T (+bias)(relu)(+resid)
// BM x 256 tile, BK=64, 8 waves (2M x 4N), double-buffered LDS.
// Sync per K-tile t (buf c=t&1):
//   lgkmcnt(0); barrier            -> all waves done READING buf c^1
//   stage(t+1 -> buf c^1)          -> safe: nobody reads c^1 now
//   vmcnt(LOADS)                   -> my t-loads (issued last iter) landed;
//                                     t+1's LOADS remain in flight (counted!)
//   barrier                        -> ALL waves' t-loads landed; buf c valid
//   ds_read frags (XOR-swizzled) + MFMA
// LDS swizzle: storage elem = row*64 + (k ^ ((row&7)<<3)); staged via linear
// global_load_lds dest + inverse-permuted per-lane GLOBAL source (involution).
// ---------------------------------------------------------------------------
template<int BM, typename TC, bool BIAS, bool RELU, bool RESID>
__global__ __launch_bounds__(512, 2) void gemm_pipe_kernel(
    const bf16* __restrict__ A, const bf16* __restrict__ Bt,
    TC* __restrict__ C, const float* __restrict__ bias,
    const float* __restrict__ resid, int M, int N, int K, int nbx)
{
    constexpr int BN   = 256;
    constexpr int BK   = 64;
    constexpr int MREP = BM / 32;          // per-wave M fragments
    constexpr int AI   = (BM * BK) / 4096; // A stage instrs (256->4, 128->2)

    __shared__ __align__(16) bf16 As[2][BM * BK];
    __shared__ __align__(16) bf16 Bs[2][BN * BK];

    // bijective XCD swizzle (grids are multiples of 8)
    const int nwg = gridDim.x;
    const int swz = (blockIdx.x & 7) * (nwg >> 3) + (blockIdx.x >> 3);
    const int nby = nwg / nbx;
    const int by  = swz % nby;             // by fastest: B-panel stays hot in L2
    const int bx  = swz / nby;
    const int row0 = by * BM, col0 = bx * BN;

    const int t  = threadIdx.x;
    const int w  = t >> 6, ln = t & 63;
    const int wm = w >> 2, wn = w & 3;
    const int lr = ln & 15, hi = ln >> 4;

    // staging geometry: instr i covers rows [i*64, i*64+64); lane ln writes
    // 16B at LDS elem (i*4096 + w*512 + ln*8); that slot logically holds
    // row = i*64 + w*8 + (ln>>3), k-chunk ((ln&7) ^ (row&7))*8  [involution]
    const int srow = w * 8 + (ln >> 3);
    const int skx  = ((ln & 7) ^ (ln >> 3)) * 8;

    f32x4_t acc[MREP][4];
    #pragma unroll
    for (int m = 0; m < MREP; ++m)
        #pragma unroll
        for (int n = 0; n < 4; ++n) acc[m][n] = (f32x4_t){0.f, 0.f, 0.f, 0.f};

    const int NT = K / BK;

    // prologue: stage K-tile 0 into buf 0
    {
        const bf16* ga = A  + (size_t)(row0 + srow) * K + skx;
        const bf16* gb = Bt + (size_t)(col0 + srow) * K + skx;
        #pragma unroll
        for (int i = 0; i < AI; ++i)
            __builtin_amdgcn_global_load_lds(
                (const __attribute__((address_space(1))) void*)(ga + (size_t)i * 64 * K),
                (__attribute__((address_space(3))) void*)(&As[0][i * 4096 + w * 512]), 16, 0, 0);
        #pragma unroll
        for (int i = 0; i < 4; ++i)
            __builtin_amdgcn_global_load_lds(
                (const __attribute__((address_space(1))) void*)(gb + (size_t)i * 64 * K),
                (__attribute__((address_space(3))) void*)(&Bs[0][i * 4096 + w * 512]), 16, 0, 0);
    }

    for (int tt = 0; tt < NT; ++tt) {
        const int c = tt & 1;
        asm volatile("s_waitcnt lgkmcnt(0)" ::: "memory");
        __builtin_amdgcn_sched_barrier(0);
        __builtin_amdgcn_s_barrier();          // all reads of buf c^1 done
        __builtin_amdgcn_sched_barrier(0);
        if (tt + 1 < NT) {
            const int d = c ^ 1;
            const int kt = (tt + 1) * BK;
            const bf16* ga = A  + (size_t)(row0 + srow) * K + kt + skx;
            const bf16* gb = Bt + (size_t)(col0 + srow) * K + kt + skx;
            #pragma unroll
            for (int i = 0; i < AI; ++i)
                __builtin_amdgcn_global_load_lds(
                    (const __attribute__((address_space(1))) void*)(ga + (size_t)i * 64 * K),
                    (__attribute__((address_space(3))) void*)(&As[d][i * 4096 + w * 512]), 16, 0, 0);
            #pragma unroll
            for (int i = 0; i < 4; ++i)
                __builtin_amdgcn_global_load_lds(
                    (const __attribute__((address_space(1))) void*)(gb + (size_t)i * 64 * K),
                    (__attribute__((address_space(3))) void*)(&Bs[d][i * 4096 + w * 512]), 16, 0, 0);
            __builtin_amdgcn_sched_barrier(0);
            if constexpr (AI == 4) asm volatile("s_waitcnt vmcnt(8)" ::: "memory");
            else                   asm volatile("s_waitcnt vmcnt(6)" ::: "memory");
        } else {
            asm volatile("s_waitcnt vmcnt(0)" ::: "memory");
        }
        __builtin_amdgcn_sched_barrier(0);
        __builtin_amdgcn_s_barrier();          // buf c valid for ALL waves
        __builtin_amdgcn_sched_barrier(0);

        #pragma unroll
        for (int kk = 0; kk < 2; ++kk) {
            bf16x8_t af[MREP], bfr[4];
            #pragma unroll
            for (int m = 0; m < MREP; ++m) {
                const int row = wm * (BM / 2) + m * 16 + lr;
                af[m] = *reinterpret_cast<const bf16x8_t*>(
                    &As[c][row * 64 + ((kk * 32 + hi * 8) ^ ((row & 7) << 3))]);
            }
            #pragma unroll
            for (int n = 0; n < 4; ++n) {
                const int col = wn * 64 + n * 16 + lr;
                bfr[n] = *reinterpret_cast<const bf16x8_t*>(
                    &Bs[c][col * 64 + ((kk * 32 + hi * 8) ^ ((col & 7) << 3))]);
            }
            #pragma unroll
            for (int m = 0; m < MREP; ++m)
                #pragma unroll
                for (int n = 0; n < 4; ++n)
                    acc[m][n] = __builtin_amdgcn_mfma_f32_16x16x32_bf16(af[m], bfr[n], acc[m][n], 0, 0, 0);
        }
    }

    // epilogue: C/D layout col=lane&15, row=(lane>>4)*4+j  [verified]
    #pragma unroll
    for (int m = 0; m < MREP; ++m) {
        #pragma unroll
        for (int n = 0; n < 4; ++n) {
            const int cgl = col0 + wn * 64 + n * 16 + lr;
            #pragma unroll
            for (int j = 0; j < 4; ++j) {
                const int r = row0 + wm * (BM / 2) + m * 16 + hi * 4 + j;
                float v = acc[m][n][j];
                if constexpr (BIAS)  v += bias[cgl];
                if constexpr (RELU)  v = fmaxf(v, 0.f);
                if constexpr (RESID) v += resid[(size_t)r * N + cgl];
                storev(&C[(size_t)r * N + cgl], v);
            }
        }
    }
}

// ---------------------------------------------------------------------------
// MFMA flash attention (round-3 verified). qkv f32 [NTOK][1536]:
// q 0..511 (group-summed), k 512.., v 1024.. ; z out bf16 [NTOK][512].
// ---------------------------------------------------------------------------
#define QBLK  128
#define KVBLK 64
#define LP    72

__global__ __launch_bounds__(512) void mfma_attn_kernel(
    const float* __restrict__ qkv, bf16* __restrict__ z)
{
    const int qt = blockIdx.x;
    const int kv = blockIdx.y;
    const int b  = blockIdx.z;
    const int t  = threadIdx.x;
    const int w  = t >> 6;
    const int ln = t & 63;
    const int lr = ln & 15;
    const int hi = ln >> 4;
    const int lk = hi * 8;

    __shared__ __align__(16) bf16 Ks[KVBLK * LP];
    __shared__ __align__(16) bf16 Vt[DHEAD * LP];
    __shared__ __align__(16) bf16 Ps[QBLK * LP];

    bf16x8_t qf[2];
    {
        const int qrow = qt * QBLK + w * 16 + lr;
        const float* qp = qkv + (size_t)(b * SEQ + qrow) * NQKV + kv * 64;
        #pragma unroll
        for (int kk = 0; kk < 2; ++kk) {
            float4 x0 = *reinterpret_cast<const float4*>(qp + kk * 32 + lk);
            float4 x1 = *reinterpret_cast<const float4*>(qp + kk * 32 + lk + 4);
            bf16x8_t v;
            v[0] = tobf(x0.x); v[1] = tobf(x0.y); v[2] = tobf(x0.z); v[3] = tobf(x0.w);
            v[4] = tobf(x1.x); v[5] = tobf(x1.y); v[6] = tobf(x1.z); v[7] = tobf(x1.w);
            qf[kk] = v;
        }
    }

    f32x4_t acc_o[4];
    #pragma unroll
    for (int n = 0; n < 4; ++n) acc_o[n] = (f32x4_t){0.f, 0.f, 0.f, 0.f};
    float m_st[4] = {-1e30f, -1e30f, -1e30f, -1e30f};
    float l_st[4] = {0.f, 0.f, 0.f, 0.f};

    const int qbase_cd = qt * QBLK + w * 16 + hi * 4;

    const int n_tiles = 2 * qt + 2;
    for (int kt = 0; kt < n_tiles; ++kt) {
        const int k0g = kt * KVBLK;
        __syncthreads();
        {
            const int r  = t >> 3;
            const int c8 = (t & 7) * 8;
            const float* kb = qkv + (size_t)(b * SEQ + k0g + r) * NQKV + 512 + kv * 64 + c8;
            float4 k0 = *reinterpret_cast<const float4*>(kb);
            float4 k1 = *reinterpret_cast<const float4*>(kb + 4);
            bf16x8_t kvv;
            kvv[0] = tobf(k0.x); kvv[1] = tobf(k0.y); kvv[2] = tobf(k0.z); kvv[3] = tobf(k0.w);
            kvv[4] = tobf(k1.x); kvv[5] = tobf(k1.y); kvv[6] = tobf(k1.z); kvv[7] = tobf(k1.w);
            *reinterpret_cast<bf16x8_t*>(&Ks[r * LP + c8]) = kvv;
        }
        {
            const int dv = w * 8;
            const float* vb = qkv + (size_t)(b * SEQ + k0g + ln) * NQKV + 1024 + kv * 64 + dv;
            float4 v0 = *reinterpret_cast<const float4*>(vb);
            float4 v1 = *reinterpret_cast<const float4*>(vb + 4);
            float vv[8] = {v0.x, v0.y, v0.z, v0.w, v1.x, v1.y, v1.z, v1.w};
            #pragma unroll
            for (int i = 0; i < 8; ++i)
                Vt[(dv + i) * LP + ln] = __float2bfloat16(vv[i]);
        }
        __syncthreads();

        f32x4_t s[4];
        #pragma unroll
        for (int n = 0; n < 4; ++n) s[n] = (f32x4_t){0.f, 0.f, 0.f, 0.f};
        #pragma unroll
        for (int kk = 0; kk < 2; ++kk) {
            #pragma unroll
            for (int n = 0; n < 4; ++n) {
                bf16x8_t kf = *reinterpret_cast<const bf16x8_t*>(&Ks[(n * 16 + lr) * LP + kk * 32 + lk]);
                s[n] = __builtin_amdgcn_mfma_f32_16x16x32_bf16(qf[kk], kf, s[n], 0, 0, 0);
            }
        }

        const bool need_mask = (kt >= 2 * qt);
        #pragma unroll
        for (int n = 0; n < 4; ++n) {
            const int colg = k0g + n * 16 + lr;
            #pragma unroll
            for (int j = 0; j < 4; ++j) {
                float val = s[n][j] * 0.125f;
                if (need_mask && colg > qbase_cd + j) val = -1e30f;
                s[n][j] = val;
            }
        }

        float alpha[4], mnew[4];
        #pragma unroll
        for (int j = 0; j < 4; ++j) {
            float mx = fmaxf(fmaxf(s[0][j], s[1][j]), fmaxf(s[2][j], s[3][j]));
            mx = fmaxf(mx, __shfl_xor(mx, 1));
            mx = fmaxf(mx, __shfl_xor(mx, 2));
            mx = fmaxf(mx, __shfl_xor(mx, 4));
            mx = fmaxf(mx, __shfl_xor(mx, 8));
            mnew[j]  = fmaxf(m_st[j], mx);
            alpha[j] = __expf(m_st[j] - mnew[j]);
            m_st[j]  = mnew[j];
        }
        float psum[4] = {0.f, 0.f, 0.f, 0.f};
        #pragma unroll
        for (int n = 0; n < 4; ++n) {
            #pragma unroll
            for (int j = 0; j < 4; ++j) {
                float p = __expf(s[n][j] - mnew[j]);
                psum[j] += p;
                Ps[(w * 16 + hi * 4 + j) * LP + n * 16 + lr] = __float2bfloat16(p);
            }
        }
        #pragma unroll
        for (int j = 0; j < 4; ++j) {
            float ps = psum[j];
            ps += __shfl_xor(ps, 1);
            ps += __shfl_xor(ps, 2);
            ps += __shfl_xor(ps, 4);
            ps += __shfl_xor(ps, 8);
            l_st[j] = l_st[j] * alpha[j] + ps;
        }
        #pragma unroll
        for (int n = 0; n < 4; ++n)
            #pragma unroll
            for (int j = 0; j < 4; ++j)
                acc_o[n][j] *= alpha[j];

        #pragma unroll
        for (int kk = 0; kk < 2; ++kk) {
            bf16x8_t pa = *reinterpret_cast<const bf16x8_t*>(&Ps[(w * 16 + lr) * LP + kk * 32 + lk]);
            #pragma unroll
            for (int n = 0; n < 4; ++n) {
                bf16x8_t vf = *reinterpret_cast<const bf16x8_t*>(&Vt[(n * 16 + lr) * LP + kk * 32 + lk]);
                acc_o[n] = __builtin_amdgcn_mfma_f32_16x16x32_bf16(pa, vf, acc_o[n], 0, 0, 0);
            }
        }
    }

    #pragma unroll
    for (int j = 0; j < 4; ++j) {
        const float inv = 1.f / l_st[j];
        const int tok = b * SEQ + qbase_cd + j;
        bf16* zp = z + (size_t)tok * (NKV * DHEAD) + kv * 64;
        #pragma unroll
        for (int n = 0; n < 4; ++n)
            zp[n * 16 + lr] = __float2bfloat16(acc_o[n][j] * inv);
    }
}

// ---------------------------------------------------------------------------
// launch
// ---------------------------------------------------------------------------
extern "C" void kernel_launch(void* const* d_in, const int* in_sizes, int n_in,
                              void* d_out, int out_size, void* d_ws, size_t ws_size,
                              hipStream_t stream)
{
    const float* resid_pre = (const float*)d_in[0];
    const float* W_Q   = (const float*)d_in[1];
    const float* W_K   = (const float*)d_in[2];
    const float* W_V   = (const float*)d_in[3];
    const float* W_O   = (const float*)d_in[4];
    const float* g1    = (const float*)d_in[5];
    const float* b1    = (const float*)d_in[6];
    const float* g2    = (const float*)d_in[7];
    const float* b2    = (const float*)d_in[8];
    const float* W_in  = (const float*)d_in[9];
    const float* b_in  = (const float*)d_in[10];
    const float* W_out = (const float*)d_in[11];
    const float* b_out = (const float*)d_in[12];
    float* out = (float*)d_out;

    char* ws = (char*)d_ws;
    const size_t OFF_WBIG  = 0;                                            // winT / woutT
    const size_t OFF_WOT   = OFF_WBIG + (size_t)DMLP * D_MODEL * 2;
    const size_t OFF_X1    = OFF_WOT  + (size_t)D_MODEL * 512 * 2;
    const size_t OFF_RMID  = OFF_X1   + (size_t)NTOK * D_MODEL * 2;
    const size_t OFF_POST  = OFF_RMID + (size_t)NTOK * D_MODEL * 4;
    const size_t OFF_WQKVT = OFF_POST;                                     // aliased in post
    const size_t OFF_QKV   = OFF_WQKVT + (size_t)NQKV * D_MODEL * 2;
    const size_t OFF_Z     = OFF_QKV   + (size_t)NTOK * NQKV * 4;

    bf16*  winT   = (bf16*) (ws + OFF_WBIG);
    bf16*  woutT  = (bf16*) (ws + OFF_WBIG);
    bf16*  woT    = (bf16*) (ws + OFF_WOT);
    bf16*  x1     = (bf16*) (ws + OFF_X1);
    float* rmid   = (float*)(ws + OFF_RMID);
    bf16*  post   = (bf16*) (ws + OFF_POST);
    bf16*  wqkvT  = (bf16*) (ws + OFF_WQKVT);
    float* qkv    = (float*)(ws + OFF_QKV);
    bf16*  zbuf   = (bf16*) (ws + OFF_Z);

    // weight prep
    transpose_f32_bf16_kernel<<<dim3(DMLP / 32, D_MODEL / 32), 256, 0, stream>>>(W_in, winT, D_MODEL, DMLP);
    head_transpose_kernel<<<dim3(D_MODEL / 32, NKV), 256, 0, stream>>>(W_Q, wqkvT, 4);
    head_transpose_kernel<<<dim3(D_MODEL / 32, NKV), 256, 0, stream>>>(W_K, wqkvT + (size_t)512  * D_MODEL, 1);
    head_transpose_kernel<<<dim3(D_MODEL / 32, NKV), 256, 0, stream>>>(W_V, wqkvT + (size_t)1024 * D_MODEL, 1);
    transpose_f32_bf16_kernel<<<dim3(D_MODEL / 32, 512 / 32), 256, 0, stream>>>(W_O, woT, 512, D_MODEL);

    // block
    rmsnorm_kernel<<<NTOK, 256, 0, stream>>>(resid_pre, g1, b1, x1);
    // qkv = x1 @ wqkvT^T   [4096 x 1536], K=2048 : 128x256 tile, grid 32x6=192
    gemm_pipe_kernel<128, float, false, false, false><<<192, 512, 0, stream>>>(
        x1, wqkvT, qkv, nullptr, nullptr, NTOK, NQKV, D_MODEL, NQKV / 256);
    mfma_attn_kernel<<<dim3(SEQ / QBLK, NKV, NB), 512, 0, stream>>>(qkv, zbuf);
    // rmid = z @ woT^T + resid_pre   [4096 x 2048], K=512 : grid 32x8=256
    gemm_pipe_kernel<128, float, false, false, true><<<256, 512, 0, stream>>>(
        zbuf, woT, rmid, nullptr, resid_pre, NTOK, D_MODEL, 512, D_MODEL / 256);
    rmsnorm_kernel<<<NTOK, 256, 0, stream>>>(rmid, g2, b2, x1);
    // post = relu(x2 @ winT^T + b_in)  [4096 x 8192], K=2048 : 256x256, grid 16x32=512
    gemm_pipe_kernel<256, bf16, true, true, false><<<512, 512, 0, stream>>>(
        x1, winT, post, b_in, nullptr, NTOK, DMLP, D_MODEL, DMLP / 256);
    transpose_f32_bf16_kernel<<<dim3(D_MODEL / 32, DMLP / 32), 256, 0, stream>>>(W_out, woutT, DMLP, D_MODEL);
    // out = post @ woutT^T + b_out + rmid  [4096 x 2048], K=8192 : grid 32x8=256
    gemm_pipe_kernel<128, float, true, false, true><<<256, 512, 0, stream>>>(
        post, woutT, out, b_out, rmid, NTOK, D_MODEL, DMLP, D_MODEL / 256);
}

// Round 5
// 544.939 us; speedup vs baseline: 8.7556x; 1.0301x over previous
//
#include <hip/hip_runtime.h>
#include <hip/hip_bf16.h>

// ---------------------------------------------------------------------------
// TransformerBlock forward, MI355X (gfx950).
// B=2, S=2048, D=2048, HQ=32 (group-summed into 8), HKV=8, DH=64, DMLP=8192.
// Round-5: FFN1 moves to an 8-phase 256x256 schedule (T3+T4+T5 over the
// verified T2 swizzle). FFN2/QKV/proj stay on the round-4 2-phase kernel.
// ---------------------------------------------------------------------------

using bf16 = __hip_bfloat16;
typedef __bf16 bf16x8_t __attribute__((ext_vector_type(8)));
typedef float  f32x4_t  __attribute__((ext_vector_type(4)));

#define D_MODEL 2048
#define SEQ     2048
#define NB      2
#define NTOK    4096
#define NKV     8
#define DHEAD   64
#define DMLP    8192
#define NQKV    1536

__device__ inline void storev(float* p, float v) { *p = v; }
__device__ inline void storev(bf16* p, float v)  { *p = __float2bfloat16(v); }

__device__ inline __bf16 tobf(float x) {
    union { __hip_bfloat16 h; __bf16 b; } u;
    u.h = __float2bfloat16(x);
    return u.b;
}

// ---------------------------------------------------------------------------
__global__ __launch_bounds__(256) void transpose_f32_bf16_kernel(
    const float* __restrict__ in, bf16* __restrict__ out, int K, int N)
{
    __shared__ float tile[32][33];
    const int n0 = blockIdx.x * 32, k0 = blockIdx.y * 32;
    const int tx = threadIdx.x & 31, ty = threadIdx.x >> 5;
    #pragma unroll
    for (int i = 0; i < 32; i += 8)
        tile[ty + i][tx] = in[(size_t)(k0 + ty + i) * N + n0 + tx];
    __syncthreads();
    #pragma unroll
    for (int i = 0; i < 32; i += 8)
        out[(size_t)(n0 + ty + i) * K + k0 + tx] = __float2bfloat16(tile[tx][ty + i]);
}

// ---------------------------------------------------------------------------
__global__ __launch_bounds__(256) void head_transpose_kernel(
    const float* __restrict__ in, bf16* __restrict__ out, int ngroup)
{
    __shared__ float tile[32][65];
    const int kv = blockIdx.y;
    const int k0 = blockIdx.x * 32;
    const int t  = threadIdx.x;
    const int e  = t & 63, kk = t >> 6;
    #pragma unroll
    for (int i = 0; i < 32; i += 4) {
        float s = 0.f;
        for (int g = 0; g < ngroup; ++g)
            s += in[((size_t)(kv * ngroup + g) * 2048 + k0 + kk + i) * 64 + e];
        tile[kk + i][e] = s;
    }
    __syncthreads();
    const int k = t & 31, ee = t >> 5;
    #pragma unroll
    for (int i = 0; i < 64; i += 8)
        out[(size_t)(kv * 64 + ee + i) * 2048 + k0 + k] = __float2bfloat16(tile[k][ee + i]);
}

// ---------------------------------------------------------------------------
__global__ __launch_bounds__(256) void rmsnorm_kernel(
    const float* __restrict__ x, const float* __restrict__ g,
    const float* __restrict__ b, bf16* __restrict__ out)
{
    const int row = blockIdx.x;
    const int t = threadIdx.x;
    const float* xr = x + (size_t)row * D_MODEL;
    float4 a0 = *reinterpret_cast<const float4*>(xr + t * 8);
    float4 a1 = *reinterpret_cast<const float4*>(xr + t * 8 + 4);
    float v[8] = {a0.x, a0.y, a0.z, a0.w, a1.x, a1.y, a1.z, a1.w};
    float sum = 0.f, sumsq = 0.f;
    #pragma unroll
    for (int j = 0; j < 8; ++j) { sum += v[j]; sumsq += v[j] * v[j]; }
    #pragma unroll
    for (int o = 1; o < 64; o <<= 1) {
        sum   += __shfl_xor(sum, o);
        sumsq += __shfl_xor(sumsq, o);
    }
    __shared__ float rs[4], rq[4];
    if ((t & 63) == 0) { rs[t >> 6] = sum; rq[t >> 6] = sumsq; }
    __syncthreads();
    sum   = rs[0] + rs[1] + rs[2] + rs[3];
    sumsq = rq[0] + rq[1] + rq[2] + rq[3];
    const float mu  = sum * (1.f / D_MODEL);
    const float var = sumsq * (1.f / D_MODEL) - mu * mu;
    const float rstd = 1.f / sqrtf(var + 1e-5f);
    const int c = t * 8;
    float4 g0 = *reinterpret_cast<const float4*>(g + c);
    float4 g1 = *reinterpret_cast<const float4*>(g + c + 4);
    float4 b0 = *reinterpret_cast<const float4*>(b + c);
    float4 b1 = *reinterpret_cast<const float4*>(b + c + 4);
    float gg[8] = {g0.x, g0.y, g0.z, g0.w, g1.x, g1.y, g1.z, g1.w};
    float bb[8] = {b0.x, b0.y, b0.z, b0.w, b1.x, b1.y, b1.z, b1.w};
    bf16* op = out + (size_t)row * D_MODEL + c;
    #pragma unroll
    for (int j = 0; j < 8; ++j) op[j] = __float2bfloat16(v[j] * rstd * gg[j] + bb[j]);
}

// ---------------------------------------------------------------------------
// Round-4 2-phase pipelined GEMM (verified): used for QKV / proj / FFN2.
// ---------------------------------------------------------------------------
template<int BM, typename TC, bool BIAS, bool RELU, bool RESID>
__global__ __launch_bounds__(512, 2) void gemm_pipe_kernel(
    const bf16* __restrict__ A, const bf16* __restrict__ Bt,
    TC* __restrict__ C, const float* __restrict__ bias,
    const float* __restrict__ resid, int M, int N, int K, int nbx)
{
    constexpr int BN   = 256;
    constexpr int BK   = 64;
    constexpr int MREP = BM / 32;
    constexpr int AI   = (BM * BK) / 4096;

    __shared__ __align__(16) bf16 As[2][BM * BK];
    __shared__ __align__(16) bf16 Bs[2][BN * BK];

    const int nwg = gridDim.x;
    const int swz = (blockIdx.x & 7) * (nwg >> 3) + (blockIdx.x >> 3);
    const int nby = nwg / nbx;
    const int by  = swz % nby;
    const int bx  = swz / nby;
    const int row0 = by * BM, col0 = bx * BN;

    const int t  = threadIdx.x;
    const int w  = t >> 6, ln = t & 63;
    const int wm = w >> 2, wn = w & 3;
    const int lr = ln & 15, hi = ln >> 4;

    const int srow = w * 8 + (ln >> 3);
    const int skx  = ((ln & 7) ^ (ln >> 3)) * 8;

    f32x4_t acc[MREP][4];
    #pragma unroll
    for (int m = 0; m < MREP; ++m)
        #pragma unroll
        for (int n = 0; n < 4; ++n) acc[m][n] = (f32x4_t){0.f, 0.f, 0.f, 0.f};

    const int NT = K / BK;

    {
        const bf16* ga = A  + (size_t)(row0 + srow) * K + skx;
        const bf16* gb = Bt + (size_t)(col0 + srow) * K + skx;
        #pragma unroll
        for (int i = 0; i < AI; ++i)
            __builtin_amdgcn_global_load_lds(
                (const __attribute__((address_space(1))) void*)(ga + (size_t)i * 64 * K),
                (__attribute__((address_space(3))) void*)(&As[0][i * 4096 + w * 512]), 16, 0, 0);
        #pragma unroll
        for (int i = 0; i < 4; ++i)
            __builtin_amdgcn_global_load_lds(
                (const __attribute__((address_space(1))) void*)(gb + (size_t)i * 64 * K),
                (__attribute__((address_space(3))) void*)(&Bs[0][i * 4096 + w * 512]), 16, 0, 0);
    }

    for (int tt = 0; tt < NT; ++tt) {
        const int c = tt & 1;
        asm volatile("s_waitcnt lgkmcnt(0)" ::: "memory");
        __builtin_amdgcn_sched_barrier(0);
        __builtin_amdgcn_s_barrier();
        __builtin_amdgcn_sched_barrier(0);
        if (tt + 1 < NT) {
            const int d = c ^ 1;
            const int kt = (tt + 1) * BK;
            const bf16* ga = A  + (size_t)(row0 + srow) * K + kt + skx;
            const bf16* gb = Bt + (size_t)(col0 + srow) * K + kt + skx;
            #pragma unroll
            for (int i = 0; i < AI; ++i)
                __builtin_amdgcn_global_load_lds(
                    (const __attribute__((address_space(1))) void*)(ga + (size_t)i * 64 * K),
                    (__attribute__((address_space(3))) void*)(&As[d][i * 4096 + w * 512]), 16, 0, 0);
            #pragma unroll
            for (int i = 0; i < 4; ++i)
                __builtin_amdgcn_global_load_lds(
                    (const __attribute__((address_space(1))) void*)(gb + (size_t)i * 64 * K),
                    (__attribute__((address_space(3))) void*)(&Bs[d][i * 4096 + w * 512]), 16, 0, 0);
            __builtin_amdgcn_sched_barrier(0);
            if constexpr (AI == 4) asm volatile("s_waitcnt vmcnt(8)" ::: "memory");
            else                   asm volatile("s_waitcnt vmcnt(6)" ::: "memory");
        } else {
            asm volatile("s_waitcnt vmcnt(0)" ::: "memory");
        }
        __builtin_amdgcn_sched_barrier(0);
        __builtin_amdgcn_s_barrier();
        __builtin_amdgcn_sched_barrier(0);

        #pragma unroll
        for (int kk = 0; kk < 2; ++kk) {
            bf16x8_t af[MREP], bfr[4];
            #pragma unroll
            for (int m = 0; m < MREP; ++m) {
                const int row = wm * (BM / 2) + m * 16 + lr;
                af[m] = *reinterpret_cast<const bf16x8_t*>(
                    &As[c][row * 64 + ((kk * 32 + hi * 8) ^ ((row & 7) << 3))]);
            }
            #pragma unroll
            for (int n = 0; n < 4; ++n) {
                const int col = wn * 64 + n * 16 + lr;
                bfr[n] = *reinterpret_cast<const bf16x8_t*>(
                    &Bs[c][col * 64 + ((kk * 32 + hi * 8) ^ ((col & 7) << 3))]);
            }
            #pragma unroll
            for (int m = 0; m < MREP; ++m)
                #pragma unroll
                for (int n = 0; n < 4; ++n)
                    acc[m][n] = __builtin_amdgcn_mfma_f32_16x16x32_bf16(af[m], bfr[n], acc[m][n], 0, 0, 0);
        }
    }

    #pragma unroll
    for (int m = 0; m < MREP; ++m) {
        #pragma unroll
        for (int n = 0; n < 4; ++n) {
            const int cgl = col0 + wn * 64 + n * 16 + lr;
            #pragma unroll
            for (int j = 0; j < 4; ++j) {
                const int r = row0 + wm * (BM / 2) + m * 16 + hi * 4 + j;
                float v = acc[m][n][j];
                if constexpr (BIAS)  v += bias[cgl];
                if constexpr (RELU)  v = fmaxf(v, 0.f);
                if constexpr (RESID) v += resid[(size_t)r * N + cgl];
                storev(&C[(size_t)r * N + cgl], v);
            }
        }
    }
}

// ---------------------------------------------------------------------------
// 8-phase 256x256 GEMM (T3+T4+T5 over T2 swizzle). 512 thr, 8 waves (2Mx4N),
// BK=64, LDS 128 KiB double-buffered. Per K-tile: 8 stage-units (64 rows x
// 64 k each, 1 global_load_lds/thread/unit), staged 2/phase in order
// [A0,A2 | B0,B1 | B2,B3 | A1,A3] for the NEXT tile. Phases consume:
//   ph0: ds_read A-mh0 (8) + B-nh0 (4); MFMA m0-3 x n0-1
//   ph1: ds_read B-nh1 (4);             MFMA m0-3 x n2-3   [vmcnt(4) gate]
//   ph2: ds_read A-mh1 (8);             MFMA m4-7 x n2-3
//   ph3: (no reads);                    MFMA m4-7 x n0-1   [vmcnt(2) gate]
// Gate ledger (2 loads/phase, X=2 entering each tile):
//   ph1 gate: outstanding 6, vmcnt(4) drains the 2 A-mh1 units this tile's
//             ph2 needs (issued prev tile ph3; 3-phase cover).
//   ph3 gate: outstanding 8, vmcnt(2) drains next tile's A0,A2,B0..B3
//             (2-phase cover), leaves its A1,A3 in flight. Never 0 mid-loop.
// Buffer safety: buf's last ds_read drains at ph2 lgkmcnt(0); two barriers
// separate it from the overwriting stage next tile.
// ---------------------------------------------------------------------------
template<typename TC, bool BIAS, bool RELU, bool RESID>
__global__ __launch_bounds__(512, 2) void gemm_8ph_kernel(
    const bf16* __restrict__ A, const bf16* __restrict__ Bt,
    TC* __restrict__ C, const float* __restrict__ bias,
    const float* __restrict__ resid, int M, int N, int K, int nbx)
{
    __shared__ __align__(16) bf16 As[2][256 * 64];
    __shared__ __align__(16) bf16 Bs[2][256 * 64];

    const int nwg = gridDim.x;
    const int swz = (blockIdx.x & 7) * (nwg >> 3) + (blockIdx.x >> 3);
    const int nby = nwg / nbx;
    const int by  = swz % nby;
    const int bx  = swz / nby;
    const int row0 = by * 256, col0 = bx * 256;

    const int t  = threadIdx.x;
    const int w  = t >> 6, ln = t & 63;
    const int wm = w >> 2, wn = w & 3;
    const int lr = ln & 15, hi = ln >> 4;
    const int rx = (lr & 7) << 3;            // read-side swizzle XOR (elems)

    const int srow = w * 8 + (ln >> 3);
    const int skx  = ((ln & 7) ^ (ln >> 3)) * 8;

#define STAGE_A8(u, dbuf, kt)                                                   \
    __builtin_amdgcn_global_load_lds(                                           \
        (const __attribute__((address_space(1))) void*)(A + (size_t)(row0 + (u) * 64 + srow) * K + (kt) + skx), \
        (__attribute__((address_space(3))) void*)(&As[dbuf][(u) * 4096 + w * 512]), 16, 0, 0)
#define STAGE_B8(u, dbuf, kt)                                                   \
    __builtin_amdgcn_global_load_lds(                                           \
        (const __attribute__((address_space(1))) void*)(Bt + (size_t)(col0 + (u) * 64 + srow) * K + (kt) + skx), \
        (__attribute__((address_space(3))) void*)(&Bs[dbuf][(u) * 4096 + w * 512]), 16, 0, 0)
#define PH_BAR                                                                  \
    __builtin_amdgcn_sched_barrier(0);                                          \
    __builtin_amdgcn_s_barrier();                                               \
    __builtin_amdgcn_sched_barrier(0)
#define LGKM0                                                                   \
    asm volatile("s_waitcnt lgkmcnt(0)" ::: "memory");                          \
    __builtin_amdgcn_sched_barrier(0)

    f32x4_t acc[8][4];
    #pragma unroll
    for (int m = 0; m < 8; ++m)
        #pragma unroll
        for (int n = 0; n < 4; ++n) acc[m][n] = (f32x4_t){0.f, 0.f, 0.f, 0.f};

    bf16x8_t af[4][2];    // current mh's A fragments
    bf16x8_t bfr[4][2];   // all 4 n fragments, live across the tile

    const int NT = K / 64;

    // prologue: tile 0's 8 units, consumption-priority order
    STAGE_A8(0, 0, 0); STAGE_A8(2, 0, 0);
    STAGE_B8(0, 0, 0); STAGE_B8(1, 0, 0); STAGE_B8(2, 0, 0); STAGE_B8(3, 0, 0);
    STAGE_A8(1, 0, 0); STAGE_A8(3, 0, 0);
    asm volatile("s_waitcnt vmcnt(2)" ::: "memory");
    PH_BAR;

    for (int tt = 0; tt < NT; ++tt) {
        const int c  = tt & 1, d = c ^ 1;
        const int kn = (tt + 1) * 64;
        const bool pf = (tt + 1 < NT);

        // ---------------- phase 0 ----------------
        #pragma unroll
        for (int mq = 0; mq < 4; ++mq) {
            const int row = wm * 128 + mq * 16 + lr;
            #pragma unroll
            for (int kk = 0; kk < 2; ++kk)
                af[mq][kk] = *reinterpret_cast<const bf16x8_t*>(
                    &As[c][row * 64 + ((kk * 32 + hi * 8) ^ rx)]);
        }
        #pragma unroll
        for (int n = 0; n < 2; ++n) {
            const int col = wn * 64 + n * 16 + lr;
            #pragma unroll
            for (int kk = 0; kk < 2; ++kk)
                bfr[n][kk] = *reinterpret_cast<const bf16x8_t*>(
                    &Bs[c][col * 64 + ((kk * 32 + hi * 8) ^ rx)]);
        }
        if (pf) { STAGE_A8(0, d, kn); STAGE_A8(2, d, kn); }
        PH_BAR;
        LGKM0;
        __builtin_amdgcn_s_setprio(1);
        #pragma unroll
        for (int mq = 0; mq < 4; ++mq)
            #pragma unroll
            for (int n = 0; n < 2; ++n)
                #pragma unroll
                for (int kk = 0; kk < 2; ++kk)
                    acc[mq][n] = __builtin_amdgcn_mfma_f32_16x16x32_bf16(af[mq][kk], bfr[n][kk], acc[mq][n], 0, 0, 0);
        __builtin_amdgcn_s_setprio(0);
        PH_BAR;

        // ---------------- phase 1 ----------------
        #pragma unroll
        for (int n = 2; n < 4; ++n) {
            const int col = wn * 64 + n * 16 + lr;
            #pragma unroll
            for (int kk = 0; kk < 2; ++kk)
                bfr[n][kk] = *reinterpret_cast<const bf16x8_t*>(
                    &Bs[c][col * 64 + ((kk * 32 + hi * 8) ^ rx)]);
        }
        if (pf) { STAGE_B8(0, d, kn); STAGE_B8(1, d, kn); }
        __builtin_amdgcn_sched_barrier(0);
        if (pf) { asm volatile("s_waitcnt vmcnt(4)" ::: "memory"); }
        else    { asm volatile("s_waitcnt vmcnt(0)" ::: "memory"); }
        PH_BAR;
        LGKM0;
        __builtin_amdgcn_s_setprio(1);
        #pragma unroll
        for (int mq = 0; mq < 4; ++mq)
            #pragma unroll
            for (int n = 2; n < 4; ++n)
                #pragma unroll
                for (int kk = 0; kk < 2; ++kk)
                    acc[mq][n] = __builtin_amdgcn_mfma_f32_16x16x32_bf16(af[mq][kk], bfr[n][kk], acc[mq][n], 0, 0, 0);
        __builtin_amdgcn_s_setprio(0);
        PH_BAR;

        // ---------------- phase 2 ----------------
        #pragma unroll
        for (int mq = 0; mq < 4; ++mq) {
            const int row = wm * 128 + 64 + mq * 16 + lr;
            #pragma unroll
            for (int kk = 0; kk < 2; ++kk)
                af[mq][kk] = *reinterpret_cast<const bf16x8_t*>(
                    &As[c][row * 64 + ((kk * 32 + hi * 8) ^ rx)]);
        }
        if (pf) { STAGE_B8(2, d, kn); STAGE_B8(3, d, kn); }
        PH_BAR;
        LGKM0;
        __builtin_amdgcn_s_setprio(1);
        #pragma unroll
        for (int mq = 0; mq < 4; ++mq)
            #pragma unroll
            for (int n = 2; n < 4; ++n)
                #pragma unroll
                for (int kk = 0; kk < 2; ++kk)
                    acc[4 + mq][n] = __builtin_amdgcn_mfma_f32_16x16x32_bf16(af[mq][kk], bfr[n][kk], acc[4 + mq][n], 0, 0, 0);
        __builtin_amdgcn_s_setprio(0);
        PH_BAR;

        // ---------------- phase 3 ----------------
        if (pf) {
            STAGE_A8(1, d, kn); STAGE_A8(3, d, kn);
            __builtin_amdgcn_sched_barrier(0);
            asm volatile("s_waitcnt vmcnt(2)" ::: "memory");
        }
        PH_BAR;
        __builtin_amdgcn_s_setprio(1);
        #pragma unroll
        for (int mq = 0; mq < 4; ++mq)
            #pragma unroll
            for (int n = 0; n < 2; ++n)
                #pragma unroll
                for (int kk = 0; kk < 2; ++kk)
                    acc[4 + mq][n] = __builtin_amdgcn_mfma_f32_16x16x32_bf16(af[mq][kk], bfr[n][kk], acc[4 + mq][n], 0, 0, 0);
        __builtin_amdgcn_s_setprio(0);
        PH_BAR;
    }

    // epilogue: C/D layout col=lane&15, row=(lane>>4)*4+j  [verified]
    #pragma unroll
    for (int m = 0; m < 8; ++m) {
        #pragma unroll
        for (int n = 0; n < 4; ++n) {
            const int cgl = col0 + wn * 64 + n * 16 + lr;
            #pragma unroll
            for (int j = 0; j < 4; ++j) {
                const int r = row0 + wm * 128 + m * 16 + hi * 4 + j;
                float v = acc[m][n][j];
                if constexpr (BIAS)  v += bias[cgl];
                if constexpr (RELU)  v = fmaxf(v, 0.f);
                if constexpr (RESID) v += resid[(size_t)r * N + cgl];
                storev(&C[(size_t)r * N + cgl], v);
            }
        }
    }
#undef STAGE_A8
#undef STAGE_B8
#undef PH_BAR
#undef LGKM0
}

// ---------------------------------------------------------------------------
// MFMA flash attention (round-3 verified).
// ---------------------------------------------------------------------------
#define QBLK  128
#define KVBLK 64
#define LP    72

__global__ __launch_bounds__(512) void mfma_attn_kernel(
    const float* __restrict__ qkv, bf16* __restrict__ z)
{
    const int qt = blockIdx.x;
    const int kv = blockIdx.y;
    const int b  = blockIdx.z;
    const int t  = threadIdx.x;
    const int w  = t >> 6;
    const int ln = t & 63;
    const int lr = ln & 15;
    const int hi = ln >> 4;
    const int lk = hi * 8;

    __shared__ __align__(16) bf16 Ks[KVBLK * LP];
    __shared__ __align__(16) bf16 Vt[DHEAD * LP];
    __shared__ __align__(16) bf16 Ps[QBLK * LP];

    bf16x8_t qf[2];
    {
        const int qrow = qt * QBLK + w * 16 + lr;
        const float* qp = qkv + (size_t)(b * SEQ + qrow) * NQKV + kv * 64;
        #pragma unroll
        for (int kk = 0; kk < 2; ++kk) {
            float4 x0 = *reinterpret_cast<const float4*>(qp + kk * 32 + lk);
            float4 x1 = *reinterpret_cast<const float4*>(qp + kk * 32 + lk + 4);
            bf16x8_t v;
            v[0] = tobf(x0.x); v[1] = tobf(x0.y); v[2] = tobf(x0.z); v[3] = tobf(x0.w);
            v[4] = tobf(x1.x); v[5] = tobf(x1.y); v[6] = tobf(x1.z); v[7] = tobf(x1.w);
            qf[kk] = v;
        }
    }

    f32x4_t acc_o[4];
    #pragma unroll
    for (int n = 0; n < 4; ++n) acc_o[n] = (f32x4_t){0.f, 0.f, 0.f, 0.f};
    float m_st[4] = {-1e30f, -1e30f, -1e30f, -1e30f};
    float l_st[4] = {0.f, 0.f, 0.f, 0.f};

    const int qbase_cd = qt * QBLK + w * 16 + hi * 4;

    const int n_tiles = 2 * qt + 2;
    for (int kt = 0; kt < n_tiles; ++kt) {
        const int k0g = kt * KVBLK;
        __syncthreads();
        {
            const int r  = t >> 3;
            const int c8 = (t & 7) * 8;
            const float* kb = qkv + (size_t)(b * SEQ + k0g + r) * NQKV + 512 + kv * 64 + c8;
            float4 k0 = *reinterpret_cast<const float4*>(kb);
            float4 k1 = *reinterpret_cast<const float4*>(kb + 4);
            bf16x8_t kvv;
            kvv[0] = tobf(k0.x); kvv[1] = tobf(k0.y); kvv[2] = tobf(k0.z); kvv[3] = tobf(k0.w);
            kvv[4] = tobf(k1.x); kvv[5] = tobf(k1.y); kvv[6] = tobf(k1.z); kvv[7] = tobf(k1.w);
            *reinterpret_cast<bf16x8_t*>(&Ks[r * LP + c8]) = kvv;
        }
        {
            const int dv = w * 8;
            const float* vb = qkv + (size_t)(b * SEQ + k0g + ln) * NQKV + 1024 + kv * 64 + dv;
            float4 v0 = *reinterpret_cast<const float4*>(vb);
            float4 v1 = *reinterpret_cast<const float4*>(vb + 4);
            float vv[8] = {v0.x, v0.y, v0.z, v0.w, v1.x, v1.y, v1.z, v1.w};
            #pragma unroll
            for (int i = 0; i < 8; ++i)
                Vt[(dv + i) * LP + ln] = __float2bfloat16(vv[i]);
        }
        __syncthreads();

        f32x4_t s[4];
        #pragma unroll
        for (int n = 0; n < 4; ++n) s[n] = (f32x4_t){0.f, 0.f, 0.f, 0.f};
        #pragma unroll
        for (int kk = 0; kk < 2; ++kk) {
            #pragma unroll
            for (int n = 0; n < 4; ++n) {
                bf16x8_t kf = *reinterpret_cast<const bf16x8_t*>(&Ks[(n * 16 + lr) * LP + kk * 32 + lk]);
                s[n] = __builtin_amdgcn_mfma_f32_16x16x32_bf16(qf[kk], kf, s[n], 0, 0, 0);
            }
        }

        const bool need_mask = (kt >= 2 * qt);
        #pragma unroll
        for (int n = 0; n < 4; ++n) {
            const int colg = k0g + n * 16 + lr;
            #pragma unroll
            for (int j = 0; j < 4; ++j) {
                float val = s[n][j] * 0.125f;
                if (need_mask && colg > qbase_cd + j) val = -1e30f;
                s[n][j] = val;
            }
        }

        float alpha[4], mnew[4];
        #pragma unroll
        for (int j = 0; j < 4; ++j) {
            float mx = fmaxf(fmaxf(s[0][j], s[1][j]), fmaxf(s[2][j], s[3][j]));
            mx = fmaxf(mx, __shfl_xor(mx, 1));
            mx = fmaxf(mx, __shfl_xor(mx, 2));
            mx = fmaxf(mx, __shfl_xor(mx, 4));
            mx = fmaxf(mx, __shfl_xor(mx, 8));
            mnew[j]  = fmaxf(m_st[j], mx);
            alpha[j] = __expf(m_st[j] - mnew[j]);
            m_st[j]  = mnew[j];
        }
        float psum[4] = {0.f, 0.f, 0.f, 0.f};
        #pragma unroll
        for (int n = 0; n < 4; ++n) {
            #pragma unroll
            for (int j = 0; j < 4; ++j) {
                float p = __expf(s[n][j] - mnew[j]);
                psum[j] += p;
                Ps[(w * 16 + hi * 4 + j) * LP + n * 16 + lr] = __float2bfloat16(p);
            }
        }
        #pragma unroll
        for (int j = 0; j < 4; ++j) {
            float ps = psum[j];
            ps += __shfl_xor(ps, 1);
            ps += __shfl_xor(ps, 2);
            ps += __shfl_xor(ps, 4);
            ps += __shfl_xor(ps, 8);
            l_st[j] = l_st[j] * alpha[j] + ps;
        }
        #pragma unroll
        for (int n = 0; n < 4; ++n)
            #pragma unroll
            for (int j = 0; j < 4; ++j)
                acc_o[n][j] *= alpha[j];

        #pragma unroll
        for (int kk = 0; kk < 2; ++kk) {
            bf16x8_t pa = *reinterpret_cast<const bf16x8_t*>(&Ps[(w * 16 + lr) * LP + kk * 32 + lk]);
            #pragma unroll
            for (int n = 0; n < 4; ++n) {
                bf16x8_t vf = *reinterpret_cast<const bf16x8_t*>(&Vt[(n * 16 + lr) * LP + kk * 32 + lk]);
                acc_o[n] = __builtin_amdgcn_mfma_f32_16x16x32_bf16(pa, vf, acc_o[n], 0, 0, 0);
            }
        }
    }

    #pragma unroll
    for (int j = 0; j < 4; ++j) {
        const float inv = 1.f / l_st[j];
        const int tok = b * SEQ + qbase_cd + j;
        bf16* zp = z + (size_t)tok * (NKV * DHEAD) + kv * 64;
        #pragma unroll
        for (int n = 0; n < 4; ++n)
            zp[n * 16 + lr] = __float2bfloat16(acc_o[n][j] * inv);
    }
}

// ---------------------------------------------------------------------------
// launch
// ---------------------------------------------------------------------------
extern "C" void kernel_launch(void* const* d_in, const int* in_sizes, int n_in,
                              void* d_out, int out_size, void* d_ws, size_t ws_size,
                              hipStream_t stream)
{
    const float* resid_pre = (const float*)d_in[0];
    const float* W_Q   = (const float*)d_in[1];
    const float* W_K   = (const float*)d_in[2];
    const float* W_V   = (const float*)d_in[3];
    const float* W_O   = (const float*)d_in[4];
    const float* g1    = (const float*)d_in[5];
    const float* b1    = (const float*)d_in[6];
    const float* g2    = (const float*)d_in[7];
    const float* b2    = (const float*)d_in[8];
    const float* W_in  = (const float*)d_in[9];
    const float* b_in  = (const float*)d_in[10];
    const float* W_out = (const float*)d_in[11];
    const float* b_out = (const float*)d_in[12];
    float* out = (float*)d_out;

    char* ws = (char*)d_ws;
    const size_t OFF_WBIG  = 0;                                            // winT / woutT
    const size_t OFF_WOT   = OFF_WBIG + (size_t)DMLP * D_MODEL * 2;
    const size_t OFF_X1    = OFF_WOT  + (size_t)D_MODEL * 512 * 2;
    const size_t OFF_RMID  = OFF_X1   + (size_t)NTOK * D_MODEL * 2;
    const size_t OFF_POST  = OFF_RMID + (size_t)NTOK * D_MODEL * 4;
    const size_t OFF_WQKVT = OFF_POST;                                     // aliased in post
    const size_t OFF_QKV   = OFF_WQKVT + (size_t)NQKV * D_MODEL * 2;
    const size_t OFF_Z     = OFF_QKV   + (size_t)NTOK * NQKV * 4;

    bf16*  winT   = (bf16*) (ws + OFF_WBIG);
    bf16*  woutT  = (bf16*) (ws + OFF_WBIG);
    bf16*  woT    = (bf16*) (ws + OFF_WOT);
    bf16*  x1     = (bf16*) (ws + OFF_X1);
    float* rmid   = (float*)(ws + OFF_RMID);
    bf16*  post   = (bf16*) (ws + OFF_POST);
    bf16*  wqkvT  = (bf16*) (ws + OFF_WQKVT);
    float* qkv    = (float*)(ws + OFF_QKV);
    bf16*  zbuf   = (bf16*) (ws + OFF_Z);

    // weight prep
    transpose_f32_bf16_kernel<<<dim3(DMLP / 32, D_MODEL / 32), 256, 0, stream>>>(W_in, winT, D_MODEL, DMLP);
    head_transpose_kernel<<<dim3(D_MODEL / 32, NKV), 256, 0, stream>>>(W_Q, wqkvT, 4);
    head_transpose_kernel<<<dim3(D_MODEL / 32, NKV), 256, 0, stream>>>(W_K, wqkvT + (size_t)512  * D_MODEL, 1);
    head_transpose_kernel<<<dim3(D_MODEL / 32, NKV), 256, 0, stream>>>(W_V, wqkvT + (size_t)1024 * D_MODEL, 1);
    transpose_f32_bf16_kernel<<<dim3(D_MODEL / 32, 512 / 32), 256, 0, stream>>>(W_O, woT, 512, D_MODEL);

    // block
    rmsnorm_kernel<<<NTOK, 256, 0, stream>>>(resid_pre, g1, b1, x1);
    // qkv = x1 @ wqkvT^T   [4096 x 1536], K=2048 : 2ph 128x256, grid 192
    gemm_pipe_kernel<128, float, false, false, false><<<192, 512, 0, stream>>>(
        x1, wqkvT, qkv, nullptr, nullptr, NTOK, NQKV, D_MODEL, NQKV / 256);
    mfma_attn_kernel<<<dim3(SEQ / QBLK, NKV, NB), 512, 0, stream>>>(qkv, zbuf);
    // rmid = z @ woT^T + resid_pre   [4096 x 2048], K=512 : 2ph, grid 256
    gemm_pipe_kernel<128, float, false, false, true><<<256, 512, 0, stream>>>(
        zbuf, woT, rmid, nullptr, resid_pre, NTOK, D_MODEL, 512, D_MODEL / 256);
    rmsnorm_kernel<<<NTOK, 256, 0, stream>>>(rmid, g2, b2, x1);
    // post = relu(x2 @ winT^T + b_in)  [4096 x 8192], K=2048 : 8-PHASE 256x256, grid 16x32=512
    gemm_8ph_kernel<bf16, true, true, false><<<512, 512, 0, stream>>>(
        x1, winT, post, b_in, nullptr, NTOK, DMLP, D_MODEL, DMLP / 256);
    transpose_f32_bf16_kernel<<<dim3(D_MODEL / 32, DMLP / 32), 256, 0, stream>>>(W_out, woutT, DMLP, D_MODEL);
    // out = post @ woutT^T + b_out + rmid  [4096 x 2048], K=8192 : 2ph, grid 256
    gemm_pipe_kernel<128, float, true, false, true><<<256, 512, 0, stream>>>(
        post, woutT, out, b_out, rmid, NTOK, D_MODEL, DMLP, D_MODEL / 256);
}

// Round 6
// 510.648 us; speedup vs baseline: 9.3436x; 1.0672x over previous
//
#include <hip/hip_runtime.h>
#include <hip/hip_bf16.h>

// ---------------------------------------------------------------------------
// TransformerBlock forward, MI355X (gfx950).
// B=2, S=2048, D=2048, HQ=32 (group-summed into 8), HKV=8, DH=64, DMLP=8192.
// Round-6: 2-phase GEMM templated on <BM,BN>; FFN2/QKV/proj move to 128x128
// (64 KB LDS -> 2 blocks/CU for cross-block barrier-drain overlap, m97/m114
// mechanism). FFN1 keeps the round-5 8-phase 256x256 kernel.
// ---------------------------------------------------------------------------

using bf16 = __hip_bfloat16;
typedef __bf16 bf16x8_t __attribute__((ext_vector_type(8)));
typedef float  f32x4_t  __attribute__((ext_vector_type(4)));

#define D_MODEL 2048
#define SEQ     2048
#define NB      2
#define NTOK    4096
#define NKV     8
#define DHEAD   64
#define DMLP    8192
#define NQKV    1536

__device__ inline void storev(float* p, float v) { *p = v; }
__device__ inline void storev(bf16* p, float v)  { *p = __float2bfloat16(v); }

__device__ inline __bf16 tobf(float x) {
    union { __hip_bfloat16 h; __bf16 b; } u;
    u.h = __float2bfloat16(x);
    return u.b;
}

// ---------------------------------------------------------------------------
__global__ __launch_bounds__(256) void transpose_f32_bf16_kernel(
    const float* __restrict__ in, bf16* __restrict__ out, int K, int N)
{
    __shared__ float tile[32][33];
    const int n0 = blockIdx.x * 32, k0 = blockIdx.y * 32;
    const int tx = threadIdx.x & 31, ty = threadIdx.x >> 5;
    #pragma unroll
    for (int i = 0; i < 32; i += 8)
        tile[ty + i][tx] = in[(size_t)(k0 + ty + i) * N + n0 + tx];
    __syncthreads();
    #pragma unroll
    for (int i = 0; i < 32; i += 8)
        out[(size_t)(n0 + ty + i) * K + k0 + tx] = __float2bfloat16(tile[tx][ty + i]);
}

// ---------------------------------------------------------------------------
__global__ __launch_bounds__(256) void head_transpose_kernel(
    const float* __restrict__ in, bf16* __restrict__ out, int ngroup)
{
    __shared__ float tile[32][65];
    const int kv = blockIdx.y;
    const int k0 = blockIdx.x * 32;
    const int t  = threadIdx.x;
    const int e  = t & 63, kk = t >> 6;
    #pragma unroll
    for (int i = 0; i < 32; i += 4) {
        float s = 0.f;
        for (int g = 0; g < ngroup; ++g)
            s += in[((size_t)(kv * ngroup + g) * 2048 + k0 + kk + i) * 64 + e];
        tile[kk + i][e] = s;
    }
    __syncthreads();
    const int k = t & 31, ee = t >> 5;
    #pragma unroll
    for (int i = 0; i < 64; i += 8)
        out[(size_t)(kv * 64 + ee + i) * 2048 + k0 + k] = __float2bfloat16(tile[k][ee + i]);
}

// ---------------------------------------------------------------------------
__global__ __launch_bounds__(256) void rmsnorm_kernel(
    const float* __restrict__ x, const float* __restrict__ g,
    const float* __restrict__ b, bf16* __restrict__ out)
{
    const int row = blockIdx.x;
    const int t = threadIdx.x;
    const float* xr = x + (size_t)row * D_MODEL;
    float4 a0 = *reinterpret_cast<const float4*>(xr + t * 8);
    float4 a1 = *reinterpret_cast<const float4*>(xr + t * 8 + 4);
    float v[8] = {a0.x, a0.y, a0.z, a0.w, a1.x, a1.y, a1.z, a1.w};
    float sum = 0.f, sumsq = 0.f;
    #pragma unroll
    for (int j = 0; j < 8; ++j) { sum += v[j]; sumsq += v[j] * v[j]; }
    #pragma unroll
    for (int o = 1; o < 64; o <<= 1) {
        sum   += __shfl_xor(sum, o);
        sumsq += __shfl_xor(sumsq, o);
    }
    __shared__ float rs[4], rq[4];
    if ((t & 63) == 0) { rs[t >> 6] = sum; rq[t >> 6] = sumsq; }
    __syncthreads();
    sum   = rs[0] + rs[1] + rs[2] + rs[3];
    sumsq = rq[0] + rq[1] + rq[2] + rq[3];
    const float mu  = sum * (1.f / D_MODEL);
    const float var = sumsq * (1.f / D_MODEL) - mu * mu;
    const float rstd = 1.f / sqrtf(var + 1e-5f);
    const int c = t * 8;
    float4 g0 = *reinterpret_cast<const float4*>(g + c);
    float4 g1 = *reinterpret_cast<const float4*>(g + c + 4);
    float4 b0 = *reinterpret_cast<const float4*>(b + c);
    float4 b1 = *reinterpret_cast<const float4*>(b + c + 4);
    float gg[8] = {g0.x, g0.y, g0.z, g0.w, g1.x, g1.y, g1.z, g1.w};
    float bb[8] = {b0.x, b0.y, b0.z, b0.w, b1.x, b1.y, b1.z, b1.w};
    bf16* op = out + (size_t)row * D_MODEL + c;
    #pragma unroll
    for (int j = 0; j < 8; ++j) op[j] = __float2bfloat16(v[j] * rstd * gg[j] + bb[j]);
}

// ---------------------------------------------------------------------------
// 2-phase pipelined GEMM (round-4 verified structure), now <BM,BN>.
// 8 waves (2M x 4N); per-wave BM/2 x BN/4; counted-vmcnt dbuf; T2 swizzle.
// Gate = vmcnt(LD) where LD = loads/tile = (BM+BN)*BK/4096.
// ---------------------------------------------------------------------------
template<int BM, int BN, typename TC, bool BIAS, bool RELU, bool RESID>
__global__ __launch_bounds__(512, 2) void gemm_pipe_kernel(
    const bf16* __restrict__ A, const bf16* __restrict__ Bt,
    TC* __restrict__ C, const float* __restrict__ bias,
    const float* __restrict__ resid, int M, int N, int K, int nbx)
{
    constexpr int BK   = 64;
    constexpr int MREP = BM / 32;          // frags per wave in M (rows BM/2)
    constexpr int NREP = BN / 64;          // frags per wave in N (cols BN/4)
    constexpr int AI   = (BM * BK) / 4096; // A stage units
    constexpr int BI   = (BN * BK) / 4096; // B stage units
    constexpr int LD   = AI + BI;          // loads per K-tile

    __shared__ __align__(16) bf16 As[2][BM * BK];
    __shared__ __align__(16) bf16 Bs[2][BN * BK];

    const int nwg = gridDim.x;
    const int swz = (blockIdx.x & 7) * (nwg >> 3) + (blockIdx.x >> 3);
    const int nby = nwg / nbx;
    const int by  = swz % nby;
    const int bx  = swz / nby;
    const int row0 = by * BM, col0 = bx * BN;

    const int t  = threadIdx.x;
    const int w  = t >> 6, ln = t & 63;
    const int wm = w >> 2, wn = w & 3;
    const int lr = ln & 15, hi = ln >> 4;

    const int srow = w * 8 + (ln >> 3);
    const int skx  = ((ln & 7) ^ (ln >> 3)) * 8;

    f32x4_t acc[MREP][NREP];
    #pragma unroll
    for (int m = 0; m < MREP; ++m)
        #pragma unroll
        for (int n = 0; n < NREP; ++n) acc[m][n] = (f32x4_t){0.f, 0.f, 0.f, 0.f};

    const int NT = K / BK;

    {
        const bf16* ga = A  + (size_t)(row0 + srow) * K + skx;
        const bf16* gb = Bt + (size_t)(col0 + srow) * K + skx;
        #pragma unroll
        for (int i = 0; i < AI; ++i)
            __builtin_amdgcn_global_load_lds(
                (const __attribute__((address_space(1))) void*)(ga + (size_t)i * 64 * K),
                (__attribute__((address_space(3))) void*)(&As[0][i * 4096 + w * 512]), 16, 0, 0);
        #pragma unroll
        for (int i = 0; i < BI; ++i)
            __builtin_amdgcn_global_load_lds(
                (const __attribute__((address_space(1))) void*)(gb + (size_t)i * 64 * K),
                (__attribute__((address_space(3))) void*)(&Bs[0][i * 4096 + w * 512]), 16, 0, 0);
    }

    for (int tt = 0; tt < NT; ++tt) {
        const int c = tt & 1;
        asm volatile("s_waitcnt lgkmcnt(0)" ::: "memory");
        __builtin_amdgcn_sched_barrier(0);
        __builtin_amdgcn_s_barrier();
        __builtin_amdgcn_sched_barrier(0);
        if (tt + 1 < NT) {
            const int d = c ^ 1;
            const int kt = (tt + 1) * BK;
            const bf16* ga = A  + (size_t)(row0 + srow) * K + kt + skx;
            const bf16* gb = Bt + (size_t)(col0 + srow) * K + kt + skx;
            #pragma unroll
            for (int i = 0; i < AI; ++i)
                __builtin_amdgcn_global_load_lds(
                    (const __attribute__((address_space(1))) void*)(ga + (size_t)i * 64 * K),
                    (__attribute__((address_space(3))) void*)(&As[d][i * 4096 + w * 512]), 16, 0, 0);
            #pragma unroll
            for (int i = 0; i < BI; ++i)
                __builtin_amdgcn_global_load_lds(
                    (const __attribute__((address_space(1))) void*)(gb + (size_t)i * 64 * K),
                    (__attribute__((address_space(3))) void*)(&Bs[d][i * 4096 + w * 512]), 16, 0, 0);
            __builtin_amdgcn_sched_barrier(0);
            if constexpr (LD == 8)      asm volatile("s_waitcnt vmcnt(8)" ::: "memory");
            else if constexpr (LD == 6) asm volatile("s_waitcnt vmcnt(6)" ::: "memory");
            else                        asm volatile("s_waitcnt vmcnt(4)" ::: "memory");
        } else {
            asm volatile("s_waitcnt vmcnt(0)" ::: "memory");
        }
        __builtin_amdgcn_sched_barrier(0);
        __builtin_amdgcn_s_barrier();
        __builtin_amdgcn_sched_barrier(0);

        #pragma unroll
        for (int kk = 0; kk < 2; ++kk) {
            bf16x8_t af[MREP], bfr[NREP];
            #pragma unroll
            for (int m = 0; m < MREP; ++m) {
                const int row = wm * (BM / 2) + m * 16 + lr;
                af[m] = *reinterpret_cast<const bf16x8_t*>(
                    &As[c][row * 64 + ((kk * 32 + hi * 8) ^ ((row & 7) << 3))]);
            }
            #pragma unroll
            for (int n = 0; n < NREP; ++n) {
                const int col = wn * (BN / 4) + n * 16 + lr;
                bfr[n] = *reinterpret_cast<const bf16x8_t*>(
                    &Bs[c][col * 64 + ((kk * 32 + hi * 8) ^ ((col & 7) << 3))]);
            }
            #pragma unroll
            for (int m = 0; m < MREP; ++m)
                #pragma unroll
                for (int n = 0; n < NREP; ++n)
                    acc[m][n] = __builtin_amdgcn_mfma_f32_16x16x32_bf16(af[m], bfr[n], acc[m][n], 0, 0, 0);
        }
    }

    #pragma unroll
    for (int m = 0; m < MREP; ++m) {
        #pragma unroll
        for (int n = 0; n < NREP; ++n) {
            const int cgl = col0 + wn * (BN / 4) + n * 16 + lr;
            #pragma unroll
            for (int j = 0; j < 4; ++j) {
                const int r = row0 + wm * (BM / 2) + m * 16 + hi * 4 + j;
                float v = acc[m][n][j];
                if constexpr (BIAS)  v += bias[cgl];
                if constexpr (RELU)  v = fmaxf(v, 0.f);
                if constexpr (RESID) v += resid[(size_t)r * N + cgl];
                storev(&C[(size_t)r * N + cgl], v);
            }
        }
    }
}

// ---------------------------------------------------------------------------
// 8-phase 256x256 GEMM (round-5 verified). Used for FFN1.
// ---------------------------------------------------------------------------
template<typename TC, bool BIAS, bool RELU, bool RESID>
__global__ __launch_bounds__(512, 2) void gemm_8ph_kernel(
    const bf16* __restrict__ A, const bf16* __restrict__ Bt,
    TC* __restrict__ C, const float* __restrict__ bias,
    const float* __restrict__ resid, int M, int N, int K, int nbx)
{
    __shared__ __align__(16) bf16 As[2][256 * 64];
    __shared__ __align__(16) bf16 Bs[2][256 * 64];

    const int nwg = gridDim.x;
    const int swz = (blockIdx.x & 7) * (nwg >> 3) + (blockIdx.x >> 3);
    const int nby = nwg / nbx;
    const int by  = swz % nby;
    const int bx  = swz / nby;
    const int row0 = by * 256, col0 = bx * 256;

    const int t  = threadIdx.x;
    const int w  = t >> 6, ln = t & 63;
    const int wm = w >> 2, wn = w & 3;
    const int lr = ln & 15, hi = ln >> 4;
    const int rx = (lr & 7) << 3;

    const int srow = w * 8 + (ln >> 3);
    const int skx  = ((ln & 7) ^ (ln >> 3)) * 8;

#define STAGE_A8(u, dbuf, kt)                                                   \
    __builtin_amdgcn_global_load_lds(                                           \
        (const __attribute__((address_space(1))) void*)(A + (size_t)(row0 + (u) * 64 + srow) * K + (kt) + skx), \
        (__attribute__((address_space(3))) void*)(&As[dbuf][(u) * 4096 + w * 512]), 16, 0, 0)
#define STAGE_B8(u, dbuf, kt)                                                   \
    __builtin_amdgcn_global_load_lds(                                           \
        (const __attribute__((address_space(1))) void*)(Bt + (size_t)(col0 + (u) * 64 + srow) * K + (kt) + skx), \
        (__attribute__((address_space(3))) void*)(&Bs[dbuf][(u) * 4096 + w * 512]), 16, 0, 0)
#define PH_BAR                                                                  \
    __builtin_amdgcn_sched_barrier(0);                                          \
    __builtin_amdgcn_s_barrier();                                               \
    __builtin_amdgcn_sched_barrier(0)
#define LGKM0                                                                   \
    asm volatile("s_waitcnt lgkmcnt(0)" ::: "memory");                          \
    __builtin_amdgcn_sched_barrier(0)

    f32x4_t acc[8][4];
    #pragma unroll
    for (int m = 0; m < 8; ++m)
        #pragma unroll
        for (int n = 0; n < 4; ++n) acc[m][n] = (f32x4_t){0.f, 0.f, 0.f, 0.f};

    bf16x8_t af[4][2];
    bf16x8_t bfr[4][2];

    const int NT = K / 64;

    STAGE_A8(0, 0, 0); STAGE_A8(2, 0, 0);
    STAGE_B8(0, 0, 0); STAGE_B8(1, 0, 0); STAGE_B8(2, 0, 0); STAGE_B8(3, 0, 0);
    STAGE_A8(1, 0, 0); STAGE_A8(3, 0, 0);
    asm volatile("s_waitcnt vmcnt(2)" ::: "memory");
    PH_BAR;

    for (int tt = 0; tt < NT; ++tt) {
        const int c  = tt & 1, d = c ^ 1;
        const int kn = (tt + 1) * 64;
        const bool pf = (tt + 1 < NT);

        // ---------------- phase 0 ----------------
        #pragma unroll
        for (int mq = 0; mq < 4; ++mq) {
            const int row = wm * 128 + mq * 16 + lr;
            #pragma unroll
            for (int kk = 0; kk < 2; ++kk)
                af[mq][kk] = *reinterpret_cast<const bf16x8_t*>(
                    &As[c][row * 64 + ((kk * 32 + hi * 8) ^ rx)]);
        }
        #pragma unroll
        for (int n = 0; n < 2; ++n) {
            const int col = wn * 64 + n * 16 + lr;
            #pragma unroll
            for (int kk = 0; kk < 2; ++kk)
                bfr[n][kk] = *reinterpret_cast<const bf16x8_t*>(
                    &Bs[c][col * 64 + ((kk * 32 + hi * 8) ^ rx)]);
        }
        if (pf) { STAGE_A8(0, d, kn); STAGE_A8(2, d, kn); }
        PH_BAR;
        LGKM0;
        __builtin_amdgcn_s_setprio(1);
        #pragma unroll
        for (int mq = 0; mq < 4; ++mq)
            #pragma unroll
            for (int n = 0; n < 2; ++n)
                #pragma unroll
                for (int kk = 0; kk < 2; ++kk)
                    acc[mq][n] = __builtin_amdgcn_mfma_f32_16x16x32_bf16(af[mq][kk], bfr[n][kk], acc[mq][n], 0, 0, 0);
        __builtin_amdgcn_s_setprio(0);
        PH_BAR;

        // ---------------- phase 1 ----------------
        #pragma unroll
        for (int n = 2; n < 4; ++n) {
            const int col = wn * 64 + n * 16 + lr;
            #pragma unroll
            for (int kk = 0; kk < 2; ++kk)
                bfr[n][kk] = *reinterpret_cast<const bf16x8_t*>(
                    &Bs[c][col * 64 + ((kk * 32 + hi * 8) ^ rx)]);
        }
        if (pf) { STAGE_B8(0, d, kn); STAGE_B8(1, d, kn); }
        __builtin_amdgcn_sched_barrier(0);
        if (pf) { asm volatile("s_waitcnt vmcnt(4)" ::: "memory"); }
        else    { asm volatile("s_waitcnt vmcnt(0)" ::: "memory"); }
        PH_BAR;
        LGKM0;
        __builtin_amdgcn_s_setprio(1);
        #pragma unroll
        for (int mq = 0; mq < 4; ++mq)
            #pragma unroll
            for (int n = 2; n < 4; ++n)
                #pragma unroll
                for (int kk = 0; kk < 2; ++kk)
                    acc[mq][n] = __builtin_amdgcn_mfma_f32_16x16x32_bf16(af[mq][kk], bfr[n][kk], acc[mq][n], 0, 0, 0);
        __builtin_amdgcn_s_setprio(0);
        PH_BAR;

        // ---------------- phase 2 ----------------
        #pragma unroll
        for (int mq = 0; mq < 4; ++mq) {
            const int row = wm * 128 + 64 + mq * 16 + lr;
            #pragma unroll
            for (int kk = 0; kk < 2; ++kk)
                af[mq][kk] = *reinterpret_cast<const bf16x8_t*>(
                    &As[c][row * 64 + ((kk * 32 + hi * 8) ^ rx)]);
        }
        if (pf) { STAGE_B8(2, d, kn); STAGE_B8(3, d, kn); }
        PH_BAR;
        LGKM0;
        __builtin_amdgcn_s_setprio(1);
        #pragma unroll
        for (int mq = 0; mq < 4; ++mq)
            #pragma unroll
            for (int n = 2; n < 4; ++n)
                #pragma unroll
                for (int kk = 0; kk < 2; ++kk)
                    acc[4 + mq][n] = __builtin_amdgcn_mfma_f32_16x16x32_bf16(af[mq][kk], bfr[n][kk], acc[4 + mq][n], 0, 0, 0);
        __builtin_amdgcn_s_setprio(0);
        PH_BAR;

        // ---------------- phase 3 ----------------
        if (pf) {
            STAGE_A8(1, d, kn); STAGE_A8(3, d, kn);
            __builtin_amdgcn_sched_barrier(0);
            asm volatile("s_waitcnt vmcnt(2)" ::: "memory");
        }
        PH_BAR;
        __builtin_amdgcn_s_setprio(1);
        #pragma unroll
        for (int mq = 0; mq < 4; ++mq)
            #pragma unroll
            for (int n = 0; n < 2; ++n)
                #pragma unroll
                for (int kk = 0; kk < 2; ++kk)
                    acc[4 + mq][n] = __builtin_amdgcn_mfma_f32_16x16x32_bf16(af[mq][kk], bfr[n][kk], acc[4 + mq][n], 0, 0, 0);
        __builtin_amdgcn_s_setprio(0);
        PH_BAR;
    }

    #pragma unroll
    for (int m = 0; m < 8; ++m) {
        #pragma unroll
        for (int n = 0; n < 4; ++n) {
            const int cgl = col0 + wn * 64 + n * 16 + lr;
            #pragma unroll
            for (int j = 0; j < 4; ++j) {
                const int r = row0 + wm * 128 + m * 16 + hi * 4 + j;
                float v = acc[m][n][j];
                if constexpr (BIAS)  v += bias[cgl];
                if constexpr (RELU)  v = fmaxf(v, 0.f);
                if constexpr (RESID) v += resid[(size_t)r * N + cgl];
                storev(&C[(size_t)r * N + cgl], v);
            }
        }
    }
#undef STAGE_A8
#undef STAGE_B8
#undef PH_BAR
#undef LGKM0
}

// ---------------------------------------------------------------------------
// MFMA flash attention (round-3 verified).
// ---------------------------------------------------------------------------
#define QBLK  128
#define KVBLK 64
#define LP    72

__global__ __launch_bounds__(512) void mfma_attn_kernel(
    const float* __restrict__ qkv, bf16* __restrict__ z)
{
    const int qt = blockIdx.x;
    const int kv = blockIdx.y;
    const int b  = blockIdx.z;
    const int t  = threadIdx.x;
    const int w  = t >> 6;
    const int ln = t & 63;
    const int lr = ln & 15;
    const int hi = ln >> 4;
    const int lk = hi * 8;

    __shared__ __align__(16) bf16 Ks[KVBLK * LP];
    __shared__ __align__(16) bf16 Vt[DHEAD * LP];
    __shared__ __align__(16) bf16 Ps[QBLK * LP];

    bf16x8_t qf[2];
    {
        const int qrow = qt * QBLK + w * 16 + lr;
        const float* qp = qkv + (size_t)(b * SEQ + qrow) * NQKV + kv * 64;
        #pragma unroll
        for (int kk = 0; kk < 2; ++kk) {
            float4 x0 = *reinterpret_cast<const float4*>(qp + kk * 32 + lk);
            float4 x1 = *reinterpret_cast<const float4*>(qp + kk * 32 + lk + 4);
            bf16x8_t v;
            v[0] = tobf(x0.x); v[1] = tobf(x0.y); v[2] = tobf(x0.z); v[3] = tobf(x0.w);
            v[4] = tobf(x1.x); v[5] = tobf(x1.y); v[6] = tobf(x1.z); v[7] = tobf(x1.w);
            qf[kk] = v;
        }
    }

    f32x4_t acc_o[4];
    #pragma unroll
    for (int n = 0; n < 4; ++n) acc_o[n] = (f32x4_t){0.f, 0.f, 0.f, 0.f};
    float m_st[4] = {-1e30f, -1e30f, -1e30f, -1e30f};
    float l_st[4] = {0.f, 0.f, 0.f, 0.f};

    const int qbase_cd = qt * QBLK + w * 16 + hi * 4;

    const int n_tiles = 2 * qt + 2;
    for (int kt = 0; kt < n_tiles; ++kt) {
        const int k0g = kt * KVBLK;
        __syncthreads();
        {
            const int r  = t >> 3;
            const int c8 = (t & 7) * 8;
            const float* kb = qkv + (size_t)(b * SEQ + k0g + r) * NQKV + 512 + kv * 64 + c8;
            float4 k0 = *reinterpret_cast<const float4*>(kb);
            float4 k1 = *reinterpret_cast<const float4*>(kb + 4);
            bf16x8_t kvv;
            kvv[0] = tobf(k0.x); kvv[1] = tobf(k0.y); kvv[2] = tobf(k0.z); kvv[3] = tobf(k0.w);
            kvv[4] = tobf(k1.x); kvv[5] = tobf(k1.y); kvv[6] = tobf(k1.z); kvv[7] = tobf(k1.w);
            *reinterpret_cast<bf16x8_t*>(&Ks[r * LP + c8]) = kvv;
        }
        {
            const int dv = w * 8;
            const float* vb = qkv + (size_t)(b * SEQ + k0g + ln) * NQKV + 1024 + kv * 64 + dv;
            float4 v0 = *reinterpret_cast<const float4*>(vb);
            float4 v1 = *reinterpret_cast<const float4*>(vb + 4);
            float vv[8] = {v0.x, v0.y, v0.z, v0.w, v1.x, v1.y, v1.z, v1.w};
            #pragma unroll
            for (int i = 0; i < 8; ++i)
                Vt[(dv + i) * LP + ln] = __float2bfloat16(vv[i]);
        }
        __syncthreads();

        f32x4_t s[4];
        #pragma unroll
        for (int n = 0; n < 4; ++n) s[n] = (f32x4_t){0.f, 0.f, 0.f, 0.f};
        #pragma unroll
        for (int kk = 0; kk < 2; ++kk) {
            #pragma unroll
            for (int n = 0; n < 4; ++n) {
                bf16x8_t kf = *reinterpret_cast<const bf16x8_t*>(&Ks[(n * 16 + lr) * LP + kk * 32 + lk]);
                s[n] = __builtin_amdgcn_mfma_f32_16x16x32_bf16(qf[kk], kf, s[n], 0, 0, 0);
            }
        }

        const bool need_mask = (kt >= 2 * qt);
        #pragma unroll
        for (int n = 0; n < 4; ++n) {
            const int colg = k0g + n * 16 + lr;
            #pragma unroll
            for (int j = 0; j < 4; ++j) {
                float val = s[n][j] * 0.125f;
                if (need_mask && colg > qbase_cd + j) val = -1e30f;
                s[n][j] = val;
            }
        }

        float alpha[4], mnew[4];
        #pragma unroll
        for (int j = 0; j < 4; ++j) {
            float mx = fmaxf(fmaxf(s[0][j], s[1][j]), fmaxf(s[2][j], s[3][j]));
            mx = fmaxf(mx, __shfl_xor(mx, 1));
            mx = fmaxf(mx, __shfl_xor(mx, 2));
            mx = fmaxf(mx, __shfl_xor(mx, 4));
            mx = fmaxf(mx, __shfl_xor(mx, 8));
            mnew[j]  = fmaxf(m_st[j], mx);
            alpha[j] = __expf(m_st[j] - mnew[j]);
            m_st[j]  = mnew[j];
        }
        float psum[4] = {0.f, 0.f, 0.f, 0.f};
        #pragma unroll
        for (int n = 0; n < 4; ++n) {
            #pragma unroll
            for (int j = 0; j < 4; ++j) {
                float p = __expf(s[n][j] - mnew[j]);
                psum[j] += p;
                Ps[(w * 16 + hi * 4 + j) * LP + n * 16 + lr] = __float2bfloat16(p);
            }
        }
        #pragma unroll
        for (int j = 0; j < 4; ++j) {
            float ps = psum[j];
            ps += __shfl_xor(ps, 1);
            ps += __shfl_xor(ps, 2);
            ps += __shfl_xor(ps, 4);
            ps += __shfl_xor(ps, 8);
            l_st[j] = l_st[j] * alpha[j] + ps;
        }
        #pragma unroll
        for (int n = 0; n < 4; ++n)
            #pragma unroll
            for (int j = 0; j < 4; ++j)
                acc_o[n][j] *= alpha[j];

        #pragma unroll
        for (int kk = 0; kk < 2; ++kk) {
            bf16x8_t pa = *reinterpret_cast<const bf16x8_t*>(&Ps[(w * 16 + lr) * LP + kk * 32 + lk]);
            #pragma unroll
            for (int n = 0; n < 4; ++n) {
                bf16x8_t vf = *reinterpret_cast<const bf16x8_t*>(&Vt[(n * 16 + lr) * LP + kk * 32 + lk]);
                acc_o[n] = __builtin_amdgcn_mfma_f32_16x16x32_bf16(pa, vf, acc_o[n], 0, 0, 0);
            }
        }
    }

    #pragma unroll
    for (int j = 0; j < 4; ++j) {
        const float inv = 1.f / l_st[j];
        const int tok = b * SEQ + qbase_cd + j;
        bf16* zp = z + (size_t)tok * (NKV * DHEAD) + kv * 64;
        #pragma unroll
        for (int n = 0; n < 4; ++n)
            zp[n * 16 + lr] = __float2bfloat16(acc_o[n][j] * inv);
    }
}

// ---------------------------------------------------------------------------
// launch
// ---------------------------------------------------------------------------
extern "C" void kernel_launch(void* const* d_in, const int* in_sizes, int n_in,
                              void* d_out, int out_size, void* d_ws, size_t ws_size,
                              hipStream_t stream)
{
    const float* resid_pre = (const float*)d_in[0];
    const float* W_Q   = (const float*)d_in[1];
    const float* W_K   = (const float*)d_in[2];
    const float* W_V   = (const float*)d_in[3];
    const float* W_O   = (const float*)d_in[4];
    const float* g1    = (const float*)d_in[5];
    const float* b1    = (const float*)d_in[6];
    const float* g2    = (const float*)d_in[7];
    const float* b2    = (const float*)d_in[8];
    const float* W_in  = (const float*)d_in[9];
    const float* b_in  = (const float*)d_in[10];
    const float* W_out = (const float*)d_in[11];
    const float* b_out = (const float*)d_in[12];
    float* out = (float*)d_out;

    char* ws = (char*)d_ws;
    const size_t OFF_WBIG  = 0;                                            // winT / woutT
    const size_t OFF_WOT   = OFF_WBIG + (size_t)DMLP * D_MODEL * 2;
    const size_t OFF_X1    = OFF_WOT  + (size_t)D_MODEL * 512 * 2;
    const size_t OFF_RMID  = OFF_X1   + (size_t)NTOK * D_MODEL * 2;
    const size_t OFF_POST  = OFF_RMID + (size_t)NTOK * D_MODEL * 4;
    const size_t OFF_WQKVT = OFF_POST;                                     // aliased in post
    const size_t OFF_QKV   = OFF_WQKVT + (size_t)NQKV * D_MODEL * 2;
    const size_t OFF_Z     = OFF_QKV   + (size_t)NTOK * NQKV * 4;

    bf16*  winT   = (bf16*) (ws + OFF_WBIG);
    bf16*  woutT  = (bf16*) (ws + OFF_WBIG);
    bf16*  woT    = (bf16*) (ws + OFF_WOT);
    bf16*  x1     = (bf16*) (ws + OFF_X1);
    float* rmid   = (float*)(ws + OFF_RMID);
    bf16*  post   = (bf16*) (ws + OFF_POST);
    bf16*  wqkvT  = (bf16*) (ws + OFF_WQKVT);
    float* qkv    = (float*)(ws + OFF_QKV);
    bf16*  zbuf   = (bf16*) (ws + OFF_Z);

    // weight prep
    transpose_f32_bf16_kernel<<<dim3(DMLP / 32, D_MODEL / 32), 256, 0, stream>>>(W_in, winT, D_MODEL, DMLP);
    head_transpose_kernel<<<dim3(D_MODEL / 32, NKV), 256, 0, stream>>>(W_Q, wqkvT, 4);
    head_transpose_kernel<<<dim3(D_MODEL / 32, NKV), 256, 0, stream>>>(W_K, wqkvT + (size_t)512  * D_MODEL, 1);
    head_transpose_kernel<<<dim3(D_MODEL / 32, NKV), 256, 0, stream>>>(W_V, wqkvT + (size_t)1024 * D_MODEL, 1);
    transpose_f32_bf16_kernel<<<dim3(D_MODEL / 32, 512 / 32), 256, 0, stream>>>(W_O, woT, 512, D_MODEL);

    // block
    rmsnorm_kernel<<<NTOK, 256, 0, stream>>>(resid_pre, g1, b1, x1);
    // qkv = x1 @ wqkvT^T   [4096 x 1536], K=2048 : 2ph 128x128, grid 32x12=384
    gemm_pipe_kernel<128, 128, float, false, false, false><<<384, 512, 0, stream>>>(
        x1, wqkvT, qkv, nullptr, nullptr, NTOK, NQKV, D_MODEL, NQKV / 128);
    mfma_attn_kernel<<<dim3(SEQ / QBLK, NKV, NB), 512, 0, stream>>>(qkv, zbuf);
    // rmid = z @ woT^T + resid_pre   [4096 x 2048], K=512 : 2ph 128x128, grid 32x16=512
    gemm_pipe_kernel<128, 128, float, false, false, true><<<512, 512, 0, stream>>>(
        zbuf, woT, rmid, nullptr, resid_pre, NTOK, D_MODEL, 512, D_MODEL / 128);
    rmsnorm_kernel<<<NTOK, 256, 0, stream>>>(rmid, g2, b2, x1);
    // post = relu(x2 @ winT^T + b_in)  [4096 x 8192], K=2048 : 8-PHASE 256x256, grid 512
    gemm_8ph_kernel<bf16, true, true, false><<<512, 512, 0, stream>>>(
        x1, winT, post, b_in, nullptr, NTOK, DMLP, D_MODEL, DMLP / 256);
    transpose_f32_bf16_kernel<<<dim3(D_MODEL / 32, DMLP / 32), 256, 0, stream>>>(W_out, woutT, DMLP, D_MODEL);
    // out = post @ woutT^T + b_out + rmid  [4096 x 2048], K=8192 : 2ph 128x128, grid 32x16=512
    gemm_pipe_kernel<128, 128, float, true, false, true><<<512, 512, 0, stream>>>(
        post, woutT, out, b_out, rmid, NTOK, D_MODEL, DMLP, D_MODEL / 128);
}